// Round 14
// baseline (94.185 us; speedup 1.0000x reference)
//
#include <hip/hip_runtime.h>
#include <stdint.h>

#define BB 4
#define NN 16384
#define MM 2048
#define CC 64
#define KK 16
#define WAVES 4
#define G 16
#define NC (G * G * G)
#define SCAP 128
#define CAP 512

typedef unsigned long long u64;
typedef unsigned int u32;
typedef unsigned short u16;
typedef unsigned char u8;

// distance from scalar c to cell interval [cell/G, (cell+1)/G]
__device__ __forceinline__ float axdist(float c, int cell) {
  const float lo = (float)cell * (1.0f / (float)G);
  const float hi = (float)(cell + 1) * (1.0f / (float)G);
  float d = 0.0f;
  if (c < lo) d = lo - c;
  else if (c > hi) d = c - hi;
  return d;
}

#define LGKM_WAIT() __asm__ volatile("s_waitcnt lgkmcnt(0)" ::: "memory")

__device__ __forceinline__ u64 wave_min_u64(u64 v) {
#pragma unroll
  for (int off = 32; off > 0; off >>= 1) {
    u64 o = __shfl_xor(v, off, 64);
    v = (o < v) ? o : v;
  }
  return v;
}

// ======================= batch-local grid build: 1 block = 1 batch =======================
__global__ __launch_bounds__(1024) void build4_kernel(
    const float* __restrict__ pts, int* __restrict__ cell_start,
    float4* __restrict__ sorted, int* __restrict__ maxcnt) {
  __shared__ int hist[NC];          // counts, then exclusive starts (cursors)
  __shared__ int wsum[16];
  const int b = blockIdx.x;
  const int t = threadIdx.x;        // 0..1023
  const int lane = t & 63;
  const int wave = t >> 6;

  if (b == 0 && t == 0) *maxcnt = 0;   // kernel boundary orders this vs grid_count

  for (int i = t; i < NC; i += 1024) hist[i] = 0;
  __syncthreads();

  // ---- count: 16 points per thread ----
  const float* pb = pts + (size_t)b * NN * 3;
  int mycell[16];
#pragma unroll
  for (int j = 0; j < 16; ++j) {
    const int i = t + j * 1024;
    const float x = pb[i * 3 + 0], y = pb[i * 3 + 1], z = pb[i * 3 + 2];
    int ix = (int)(x * (float)G); ix = ix < 0 ? 0 : (ix > G - 1 ? G - 1 : ix);
    int iy = (int)(y * (float)G); iy = iy < 0 ? 0 : (iy > G - 1 ? G - 1 : iy);
    int iz = (int)(z * (float)G); iz = iz < 0 ? 0 : (iz > G - 1 ? G - 1 : iz);
    const int cell = (iz * G + iy) * G + ix;
    mycell[j] = cell;
    atomicAdd(&hist[cell], 1);
  }
  __syncthreads();

  // ---- scan: thread t owns cells [4t, 4t+4) ----
  const int base = t * 4;
  const int l0 = hist[base], l1 = hist[base + 1], l2 = hist[base + 2], l3 = hist[base + 3];
  const int s4 = l0 + l1 + l2 + l3;
  u32 inc = (u32)s4;
#pragma unroll
  for (int off = 1; off < 64; off <<= 1) {
    u32 tt = __shfl_up(inc, off, 64);
    if (lane >= off) inc += tt;
  }
  if (lane == 63) wsum[wave] = (int)inc;
  __syncthreads();
  u32 woff = 0;
  for (int w2 = 0; w2 < wave; ++w2) woff += (u32)wsum[w2];
  const int ex = (int)(woff + inc - (u32)s4);
  hist[base] = ex;
  hist[base + 1] = ex + l0;
  hist[base + 2] = ex + l0 + l1;
  hist[base + 3] = ex + l0 + l1 + l2;
  int* st = cell_start + b * (NC + 1);
  st[base] = ex;
  st[base + 1] = ex + l0;
  st[base + 2] = ex + l0 + l1;
  st[base + 3] = ex + l0 + l1 + l2;
  if (t == 0) st[NC] = NN;
  __syncthreads();

  // ---- fill: LDS cursor bump + global scatter ----
  float4* sp = sorted + (size_t)b * NN;
#pragma unroll
  for (int j = 0; j < 16; ++j) {
    const int i = t + j * 1024;
    const float x = pb[i * 3 + 0], y = pb[i * 3 + 1], z = pb[i * 3 + 2];
    const int pos = atomicAdd(&hist[mycell[j]], 1);
    sp[pos] = make_float4(x, y, z, __uint_as_float((u32)i));
  }
}

// ======================= density count: 16 lanes per center =======================
__global__ __launch_bounds__(256) void grid_count_kernel(
    const float* __restrict__ points, const int* __restrict__ cidx,
    const int* __restrict__ cell_start, const float4* __restrict__ sorted,
    int* __restrict__ counts, int* __restrict__ maxcnt) {
#pragma clang fp contract(off)
  __shared__ int bmax;
  const int sub = threadIdx.x & 15;
  const int grp = threadIdx.x >> 4;
  const int center = blockIdx.x * 16 + grp;
  const int b = center >> 11;
  if (threadIdx.x == 0) bmax = 0;
  __syncthreads();
  const float* pb = points + (size_t)b * (NN * 3);
  const int ci = cidx[center];
  const float ccx = pb[ci * 3 + 0], ccy = pb[ci * 3 + 1], ccz = pb[ci * 3 + 2];
  const float R0 = 0.05f;
  const float rc = R0 * 1.0001f + 1e-6f;
  const float rc2 = rc * rc;
  const int lox = max(0, (int)floorf((ccx - rc) * (float)G));
  const int hix = min(G - 1, (int)floorf((ccx + rc) * (float)G));
  const int loy = max(0, (int)floorf((ccy - rc) * (float)G));
  const int hiy = min(G - 1, (int)floorf((ccy + rc) * (float)G));
  const int loz = max(0, (int)floorf((ccz - rc) * (float)G));
  const int hiz = min(G - 1, (int)floorf((ccz + rc) * (float)G));
  const int cs0 = b * (NC + 1);
  const float4* sp = sorted + (size_t)b * NN;
  int cnt = 0;
  for (int zc = loz; zc <= hiz; ++zc) {
    const float dz0 = axdist(ccz, zc);
    for (int yc = loy; yc <= hiy; ++yc) {
      const float dy0 = axdist(ccy, yc);
      const float dd = dy0 * dy0 + dz0 * dz0;
      if (dd >= rc2) continue;
      const float half = sqrtf(rc2 - dd) * 1.0001f + 1e-6f;
      const int xl = max(lox, (int)floorf((ccx - half) * (float)G));
      const int xh = min(hix, (int)floorf((ccx + half) * (float)G));
      if (xl > xh) continue;
      const int row = cs0 + (zc * G + yc) * G;
      const int s0 = cell_start[row + xl];
      const int e0 = cell_start[row + xh + 1];
      for (int p = s0 + sub; p < e0; p += 16) {
        const float4 pt = sp[p];
        const float dx = pt.x - ccx, dy = pt.y - ccy, dz = pt.z - ccz;
        const float d = sqrtf((dx * dx + dy * dy) + dz * dz);
        cnt += (d < R0) ? 1 : 0;
      }
    }
  }
#pragma unroll
  for (int off = 8; off > 0; off >>= 1) cnt += __shfl_xor(cnt, off, 16);
  if (sub == 0) {
    counts[center] = cnt;
    atomicMax(&bmax, cnt);
  }
  __syncthreads();
  if (threadIdx.x == 0) atomicMax(maxcnt, bmax);
}

// ======================= topk: fast direct-collect + histogram fallback =======================
#define WALK(BODY)                                                   \
  {                                                                  \
    int ri = 0;                                                      \
    for (u32 w = (u32)lane; w < T; w += 64) {                        \
      while (rowC[ri + 1] <= w) ++ri;                                \
      const int p = (int)rowS[ri] + (int)(w - rowC[ri]);             \
      const float4 pt = sp[p];                                       \
      const float dx = pt.x - ccx, dy = pt.y - ccy, dz = pt.z - ccz; \
      const float d = sqrtf((dx * dx + dy * dy) + dz * dz);          \
      BODY                                                           \
    }                                                                \
  }

__global__ __launch_bounds__(256, 8) void grid_topk_kernel(
    const float* __restrict__ points, const float* __restrict__ features,
    const int* __restrict__ cidx, const int* __restrict__ counts,
    const int* __restrict__ maxcnt, const int* __restrict__ cell_start,
    const float4* __restrict__ sorted, float* __restrict__ out) {
#pragma clang fp contract(off)
  __shared__ u16 cand_s[WAVES][CAP];
  __shared__ u8  candb_s[WAVES][CAP];
  __shared__ u64 surv_s[WAVES][SCAP + 2];
  __shared__ u32 rowS_s[WAVES][128];
  __shared__ u32 rowC_s[WAVES][128];
  __shared__ u32 hist_s[WAVES][128];           // 32 bins x 4 replicas (slow path)

  const int lane = threadIdx.x & 63;
  const int wave = threadIdx.x >> 6;
  const int center = blockIdx.x * WAVES + wave;
  const int b = center >> 11;
  u16* cand = cand_s[wave];
  u8*  candb = candb_s[wave];
  u64* surv = surv_s[wave];
  u32* rowS = rowS_s[wave];
  u32* rowC = rowC_s[wave];
  u32* hist = hist_s[wave];
  const u64 lanemask = (((u64)1 << lane) - 1);

  const float* pb = points + (size_t)b * (NN * 3);
  const int ci = cidx[center];
  const float ccx = pb[ci * 3 + 0], ccy = pb[ci * 3 + 1], ccz = pb[ci * 3 + 2];

  const int cnt_c = counts[center];
  const float DENOM = (float)(4.0 / 3.0 * 3.141592653589793 * (0.05 * 0.05 * 0.05) + 1e-8);
  const float dens = (float)cnt_c / DENOM;
  const float dmax = (float)(*maxcnt) / DENOM + 1e-8f;
  const float r = 0.05f + 0.25f * (1.0f - dens / dmax);
  const int cs0 = b * (NC + 1);
  const float4* sp = sorted + (size_t)b * NN;

  // stage-1 radius; expected candidates self-normalize to ~cnt*(16/cnt)*1.35^3 ~ 39
  const float tA = fminf(r, fmaxf(0.055f,
      0.05f * cbrtf(16.0f / fmaxf((float)cnt_c, 0.5f)) * 1.35f));

  u32 scnt = 0;

  for (int attempt = 0; attempt < 2; ++attempt) {
    const bool fast = (attempt == 0);
    const float t_eff = fast ? tA : r;
    const bool finals = (attempt == 1) || (tA >= r);
    const float rc = t_eff * 1.0001f + 1e-6f;
    const float rc2 = rc * rc;
    const float bs1 = 32.0f / t_eff;
    const float bs2 = 1024.0f / t_eff;

    const int lox = max(0, (int)floorf((ccx - rc) * (float)G));
    const int hix = min(G - 1, (int)floorf((ccx + rc) * (float)G));
    const int loy = max(0, (int)floorf((ccy - rc) * (float)G));
    const int hiy = min(G - 1, (int)floorf((ccy + rc) * (float)G));
    const int loz = max(0, (int)floorf((ccz - rc) * (float)G));
    const int hiz = min(G - 1, (int)floorf((ccz + rc) * (float)G));

    // ---- phase 1: pruned row table ----
    const int ny = hiy - loy + 1;
    const int nrows = ny * (hiz - loz + 1);
    u32 len0 = 0, len1 = 0, st0 = 0, st1 = 0;
#pragma unroll
    for (int half_i = 0; half_i < 2; ++half_i) {
      const int rr = lane + half_i * 64;
      u32 st = 0, len = 0;
      if (rr < nrows) {
        const int zz = rr / ny, yy = rr - zz * ny;
        const int zc = loz + zz, yc = loy + yy;
        const float dz0 = axdist(ccz, zc);
        const float dy0 = axdist(ccy, yc);
        const float dd = dy0 * dy0 + dz0 * dz0;
        if (dd < rc2) {
          const float half = sqrtf(rc2 - dd) * 1.0001f + 1e-6f;
          const int xl = max(lox, (int)floorf((ccx - half) * (float)G));
          const int xh = min(hix, (int)floorf((ccx + half) * (float)G));
          if (xl <= xh) {
            const int row = cs0 + (zc * G + yc) * G;
            const int s0 = cell_start[row + xl];
            const int e0 = cell_start[row + xh + 1];
            st = (u32)s0; len = (u32)(e0 - s0);
          }
        }
      }
      if (half_i == 0) { st0 = st; len0 = len; } else { st1 = st; len1 = len; }
    }
    u32 a = len0;
#pragma unroll
    for (int off = 1; off < 64; off <<= 1) {
      u32 t = __shfl_up(a, off, 64);
      if (lane >= off) a += t;
    }
    const u32 tot0 = __shfl(a, 63, 64);
    u32 bcum = len1;
#pragma unroll
    for (int off = 1; off < 64; off <<= 1) {
      u32 t = __shfl_up(bcum, off, 64);
      if (lane >= off) bcum += t;
    }
    const u32 T = tot0 + __shfl(bcum, 63, 64);
    rowS[lane] = st0;
    rowS[lane + 64] = st1;
    rowC[lane] = a - len0;
    rowC[lane + 64] = tot0 + bcum - len1;
    LGKM_WAIT();

    if (fast) {
      // ---- FAST PATH: collect exact (d,idx) keys directly into surv ----
      // Expected ~39 candidates <= SCAP; rank-select picks the 16 smallest,
      // so no histogram threshold is needed when total <= SCAP.
      u32 scn = 0;
      {
        int riA = 0, riB = 0;
        for (u32 w = (u32)lane; w < T; w += 128) {
          while (rowC[riA + 1] <= w) ++riA;
          const int pA = (int)rowS[riA] + (int)(w - rowC[riA]);
          const float4 ptA = sp[pA];
          const u32 w2 = w + 64;
          const bool hasB = (w2 < T);
          float xB = 4e4f, yB = 4e4f, zB = 4e4f, wB = 0.0f;
          if (hasB) {
            if (riB < riA) riB = riA;
            while (rowC[riB + 1] <= w2) ++riB;
            const int pB = (int)rowS[riB] + (int)(w2 - rowC[riB]);
            const float4 ptB = sp[pB];
            xB = ptB.x; yB = ptB.y; zB = ptB.z; wB = ptB.w;
          }
          const float dxA = ptA.x - ccx, dyA = ptA.y - ccy, dzA = ptA.z - ccz;
          const float dA = sqrtf((dxA * dxA + dyA * dyA) + dzA * dzA);
          const float dxB = xB - ccx, dyB = yB - ccy, dzB = zB - ccz;
          const float dB = sqrtf((dxB * dxB + dyB * dyB) + dzB * dzB);
          const bool accA = dA < t_eff;
          const bool accB = hasB && (dB < t_eff);
          const u64 maskA = __ballot(accA);
          const u64 maskB = __ballot(accB);
          if (accA) {
            const u32 pos = scn + (u32)__popcll(maskA & lanemask);
            if (pos < (u32)SCAP)
              surv[pos] = ((u64)__float_as_uint(dA) << 32) | __float_as_uint(ptA.w);
          }
          const u32 cA = (u32)__popcll(maskA);
          if (accB) {
            const u32 pos = scn + cA + (u32)__popcll(maskB & lanemask);
            if (pos < (u32)SCAP)
              surv[pos] = ((u64)__float_as_uint(dB) << 32) | __float_as_uint(wB);
          }
          scn += cA + (u32)__popcll(maskB);
        }
      }
      scn = (u32)__shfl((int)scn, 0, 64);   // lane 0 runs max iterations -> complete
      LGKM_WAIT();
      if (scn > (u32)SCAP) continue;        // rare overflow -> full histogram path
      if (scn < (u32)KK && !finals) continue;
      scnt = scn;
      break;
    }

    // ---- SLOW PATH (attempt 1): proven histogram threshold machinery ----
    hist[lane] = 0;
    hist[lane + 64] = 0;
    LGKM_WAIT();

    u32 scn = 0;
    {
      int riA = 0, riB = 0;
      for (u32 w = (u32)lane; w < T; w += 128) {
        while (rowC[riA + 1] <= w) ++riA;
        const int pA = (int)rowS[riA] + (int)(w - rowC[riA]);
        const float4 ptA = sp[pA];
        const u32 w2 = w + 64;
        const bool hasB = (w2 < T);
        int pB = 0;
        float xB = 4e4f, yB = 4e4f, zB = 4e4f;
        if (hasB) {
          if (riB < riA) riB = riA;
          while (rowC[riB + 1] <= w2) ++riB;
          pB = (int)rowS[riB] + (int)(w2 - rowC[riB]);
          const float4 ptB = sp[pB];
          xB = ptB.x; yB = ptB.y; zB = ptB.z;
        }
        const float dxA = ptA.x - ccx, dyA = ptA.y - ccy, dzA = ptA.z - ccz;
        const float dA = sqrtf((dxA * dxA + dyA * dyA) + dzA * dzA);
        const float dxB = xB - ccx, dyB = yB - ccy, dzB = zB - ccz;
        const float dB = sqrtf((dxB * dxB + dyB * dyB) + dzB * dzB);
        const bool accA = dA < t_eff;
        const bool accB = hasB && (dB < t_eff);
        const u64 maskA = __ballot(accA);
        const u64 maskB = __ballot(accB);
        if (accA) {
          int bin = (int)(dA * bs1); bin = bin > 31 ? 31 : bin;
          atomicAdd(&hist[((lane & 3) << 5) + bin], 1u);
          const u32 pos = scn + (u32)__popcll(maskA & lanemask);
          if (pos < (u32)CAP) { cand[pos] = (u16)pA; candb[pos] = (u8)bin; }
        }
        const u32 cA = (u32)__popcll(maskA);
        if (accB) {
          int bin = (int)(dB * bs1); bin = bin > 31 ? 31 : bin;
          atomicAdd(&hist[((lane & 3) << 5) + bin], 1u);
          const u32 pos = scn + cA + (u32)__popcll(maskB & lanemask);
          if (pos < (u32)CAP) { cand[pos] = (u16)pB; candb[pos] = (u8)bin; }
        }
        scn += cA + (u32)__popcll(maskB);
      }
    }
    LGKM_WAIT();

    u32 incl = 0;
    if (lane < 32) incl = hist[lane] + hist[lane + 32] + hist[lane + 64] + hist[lane + 96];
#pragma unroll
    for (int off = 1; off < 32; off <<= 1) {
      u32 t = __shfl_up(incl, off, 32);
      if ((lane & 31) >= off) incl += t;
    }
    const u32 total = __shfl(incl, 31, 64);
    const bool overflow = total > (u32)CAP;

    if (total < (u32)KK) {
      for (u32 i = lane; i < total; i += 64) {
        const float4 pt = sp[cand[i]];
        const float dx = pt.x - ccx, dy = pt.y - ccy, dz = pt.z - ccz;
        const float d = sqrtf((dx * dx + dy * dy) + dz * dz);
        surv[i] = ((u64)__float_as_uint(d) << 32) | __float_as_uint(pt.w);
      }
      scnt = total;
      LGKM_WAIT();
      break;
    }

    u64 bm = __ballot(lane < 32 && incl >= (u32)KK);
    const int b1 = (__ffsll(bm) - 1);
    const u32 cnt_b1 = __shfl(incl, b1, 64);
    const u32 pre = (b1 > 0) ? __shfl(incl, b1 - 1, 64) : 0u;

    int b2 = 31;
    const bool need2 = (pre + cnt_b1 > (u32)SCAP);
    if (need2) {
      hist[lane] = 0;
      hist[lane + 64] = 0;
      LGKM_WAIT();
      if (!overflow) {
        for (u32 i = lane; i < total; i += 64) {
          if ((int)candb[i] == b1) {
            const float4 pt = sp[cand[i]];
            const float dx = pt.x - ccx, dy = pt.y - ccy, dz = pt.z - ccz;
            const float d = sqrtf((dx * dx + dy * dy) + dz * dz);
            int o = (int)(d * bs2) - (b1 << 5);
            o = o < 0 ? 0 : (o > 31 ? 31 : o);
            atomicAdd(&hist[((lane & 3) << 5) + o], 1u);
          }
        }
      } else {
        WALK({
          if (d < t_eff) {
            int bin = (int)(d * bs1); bin = bin > 31 ? 31 : bin;
            if (bin == b1) {
              int o = (int)(d * bs2) - (b1 << 5);
              o = o < 0 ? 0 : (o > 31 ? 31 : o);
              atomicAdd(&hist[((lane & 3) << 5) + o], 1u);
            }
          }
        })
      }
      LGKM_WAIT();
      u32 incl2 = 0;
      if (lane < 32) incl2 = hist[lane] + hist[lane + 32] + hist[lane + 64] + hist[lane + 96];
#pragma unroll
      for (int off = 1; off < 32; off <<= 1) {
        u32 t = __shfl_up(incl2, off, 32);
        if ((lane & 31) >= off) incl2 += t;
      }
      const u32 target = (u32)KK - pre;
      u64 bm2 = __ballot(lane < 32 && incl2 >= target);
      b2 = bm2 ? (__ffsll(bm2) - 1) : 31;
    }

    u32 sc = 0;
    if (!overflow) {
      for (u32 i = lane; i < total; i += 64) {
        const int bin = (int)candb[i];
        bool acc2;
        float d = 0.0f;
        u32 pw = 0;
        if (!need2) {
          acc2 = (bin <= b1);
          if (acc2) {
            const float4 pt = sp[cand[i]];
            const float dx = pt.x - ccx, dy = pt.y - ccy, dz = pt.z - ccz;
            d = sqrtf((dx * dx + dy * dy) + dz * dz);
            pw = __float_as_uint(pt.w);
          }
        } else {
          acc2 = (bin < b1);
          if (bin == b1) {
            const float4 pt = sp[cand[i]];
            const float dx = pt.x - ccx, dy = pt.y - ccy, dz = pt.z - ccz;
            d = sqrtf((dx * dx + dy * dy) + dz * dz);
            pw = __float_as_uint(pt.w);
            int o = (int)(d * bs2) - (b1 << 5);
            o = o < 0 ? 0 : (o > 31 ? 31 : o);
            acc2 = (o <= b2);
          } else if (acc2) {
            const float4 pt = sp[cand[i]];
            const float dx = pt.x - ccx, dy = pt.y - ccy, dz = pt.z - ccz;
            d = sqrtf((dx * dx + dy * dy) + dz * dz);
            pw = __float_as_uint(pt.w);
          }
        }
        const u64 mask = __ballot(acc2);
        if (acc2) {
          const u32 pos = sc + (u32)__popcll(mask & lanemask);
          if (pos < (u32)SCAP)
            surv[pos] = ((u64)__float_as_uint(d) << 32) | pw;
        }
        sc += (u32)__popcll(mask);
      }
    } else {
      WALK({
        bool acc2 = false;
        if (d < t_eff) {
          int bin = (int)(d * bs1); bin = bin > 31 ? 31 : bin;
          if (!need2) acc2 = (bin <= b1);
          else {
            int o = (int)(d * bs2) - (b1 << 5);
            o = o < 0 ? 0 : (o > 31 ? 31 : o);
            acc2 = (bin < b1) || (bin == b1 && o <= b2);
          }
        }
        const u64 mask = __ballot(acc2);
        if (acc2) {
          const u32 pos = sc + (u32)__popcll(mask & lanemask);
          if (pos < (u32)SCAP)
            surv[pos] = ((u64)__float_as_uint(d) << 32) | __float_as_uint(pt.w);
        }
        sc += (u32)__popcll(mask);
      })
    }
    sc = (u32)__shfl((int)sc, 0, 64);
    scnt = sc > (u32)SCAP ? (u32)SCAP : sc;
    LGKM_WAIT();
    break;
  }

  // ---- phase 5: fill with lowest-index masked points if short ----
  if (scnt < (u32)KK) {
    for (int base = 0; base < NN && scnt < (u32)KK; base += 64) {
      const int i = base + lane;
      const float x = pb[i * 3 + 0], y = pb[i * 3 + 1], z = pb[i * 3 + 2];
      const float dx = x - ccx, dy = y - ccy, dz = z - ccz;
      const float d = sqrtf((dx * dx + dy * dy) + dz * dz);
      u64 m = __ballot(!(d < r));
      while (m && scnt < (u32)KK) {
        const int t = __ffsll(m) - 1;
        m &= m - 1;
        if (lane == 0)
          surv[scnt] = ((u64)__float_as_uint(1e10f) << 32) | (u32)(base + t);
        scnt++;
      }
    }
    LGKM_WAIT();
  }

  // ---- phase 6: rank-based select of the KK smallest (dist, idx) keys ----
  {
    const u64 k0 = (lane < (int)scnt) ? surv[lane] : ~0ULL;
    const u64 k1 = (lane + 64 < (int)scnt) ? surv[lane + 64] : ~0ULL;
    u32 rank0 = 0, rank1 = 0;
    for (u32 j = 0; j < scnt; ++j) {
      const u64 kj = surv[j];        // wave-uniform broadcast read
      rank0 += (kj < k0) ? 1u : 0u;
      rank1 += (kj < k1) ? 1u : 0u;
    }
    if (lane < (int)scnt && rank0 < (u32)KK) rowS[rank0] = (u32)(k0 & 0xffffffffULL);
    if (lane + 64 < (int)scnt && rank1 < (u32)KK) rowS[rank1] = (u32)(k1 & 0xffffffffULL);
    LGKM_WAIT();
  }

  // ---- phase 7: feature gather, float4 vectorized (16 lanes x 4ch per k) ----
  const float* fb = features + (size_t)b * NN * CC;
  float* ob = out + (size_t)center * KK * CC;
  const int ch4 = (lane & 15) * 4;
  const int ksub = lane >> 4;
#pragma unroll
  for (int kq = 0; kq < 4; ++kq) {
    const int k = kq * 4 + ksub;
    const int nk = (int)rowS[k];
    const float4 v = *(const float4*)(fb + (size_t)nk * CC + ch4);
    *(float4*)(ob + (size_t)k * CC + ch4) = v;
  }
}

// ======================= fallback (round-1, proven) =======================
#define CH 4096
#define NCHUNK (NN / CH)

__global__ __launch_bounds__(256) void fb_count_kernel(
    const float* __restrict__ points, const int* __restrict__ cidx,
    int* __restrict__ counts, int* __restrict__ maxcnt) {
#pragma clang fp contract(off)
  __shared__ float s[CH * 3];
  const int lane = threadIdx.x & 63;
  const int wave = threadIdx.x >> 6;
  const int center = blockIdx.x * WAVES + wave;
  const int b = center >> 11;
  const float* pb = points + (size_t)b * (NN * 3);
  const int ci = cidx[center];
  const float cx = pb[ci * 3 + 0], cy = pb[ci * 3 + 1], cz = pb[ci * 3 + 2];
  int cnt = 0;
  for (int c = 0; c < NCHUNK; ++c) {
    __syncthreads();
    const float4* src = (const float4*)(pb + (size_t)c * CH * 3);
    float4* dst = (float4*)s;
    for (int i = threadIdx.x; i < CH * 3 / 4; i += 256) dst[i] = src[i];
    __syncthreads();
    for (int j = 0; j < CH / 64; ++j) {
      const int p = j * 64 + lane;
      const float dx = s[p * 3 + 0] - cx;
      const float dy = s[p * 3 + 1] - cy;
      const float dz = s[p * 3 + 2] - cz;
      const float d = sqrtf((dx * dx + dy * dy) + dz * dz);
      cnt += (d < 0.05f) ? 1 : 0;
    }
  }
#pragma unroll
  for (int off = 32; off > 0; off >>= 1) cnt += __shfl_xor(cnt, off, 64);
  if (lane == 0) { counts[center] = cnt; atomicMax(maxcnt, cnt); }
}

__global__ __launch_bounds__(256) void fb_topk_kernel(
    const float* __restrict__ points, const float* __restrict__ features,
    const int* __restrict__ cidx, const int* __restrict__ counts,
    const int* __restrict__ maxcnt, float* __restrict__ out) {
#pragma clang fp contract(off)
  __shared__ float s[CH * 3];
  const int lane = threadIdx.x & 63;
  const int wave = threadIdx.x >> 6;
  const int center = blockIdx.x * WAVES + wave;
  const int b = center >> 11;
  const float* pb = points + (size_t)b * (NN * 3);
  const int ci = cidx[center];
  const float cx = pb[ci * 3 + 0], cy = pb[ci * 3 + 1], cz = pb[ci * 3 + 2];
  const float DENOM = (float)(4.0 / 3.0 * 3.141592653589793 * (0.05 * 0.05 * 0.05) + 1e-8);
  const float dens = (float)counts[center] / DENOM;
  const float dmax = (float)(*maxcnt) / DENOM + 1e-8f;
  const float r = 0.05f + 0.25f * (1.0f - dens / dmax);
  u64 kb[KK];
#pragma unroll
  for (int i = 0; i < KK; ++i) kb[i] = ~0ULL;
  u64 worst = ~0ULL, T = ~0ULL;
  for (int c = 0; c < NCHUNK; ++c) {
    __syncthreads();
    const float4* src = (const float4*)(pb + (size_t)c * CH * 3);
    float4* dst = (float4*)s;
    for (int i = threadIdx.x; i < CH * 3 / 4; i += 256) dst[i] = src[i];
    __syncthreads();
    const int nbase = c * CH;
    for (int j = 0; j < CH / 64; ++j) {
      const int p = j * 64 + lane;
      const float dx = s[p * 3 + 0] - cx;
      const float dy = s[p * 3 + 1] - cy;
      const float dz = s[p * 3 + 2] - cz;
      const float d = sqrtf((dx * dx + dy * dy) + dz * dz);
      const float dm = (d < r) ? d : 1e10f;
      const u64 key = ((u64)__float_as_uint(dm) << 32) | (unsigned)(nbase + p);
      if (key < T && key < worst) {
        u64 cc = key;
#pragma unroll
        for (int i = 0; i < KK; ++i) {
          const bool lt = kb[i] < cc;
          const u64 lo = lt ? kb[i] : cc;
          const u64 hi = lt ? cc : kb[i];
          kb[i] = lo; cc = hi;
        }
        worst = kb[KK - 1];
      }
    }
    if (c == 0) {
      u64 t[KK];
#pragma unroll
      for (int i = 0; i < KK; ++i) t[i] = kb[i];
      u64 g = 0;
#pragma unroll
      for (int k = 0; k < KK; ++k) {
        g = wave_min_u64(t[0]);
        if (t[0] == g) {
#pragma unroll
          for (int i = 0; i < KK - 1; ++i) t[i] = t[i + 1];
          t[KK - 1] = ~0ULL;
        }
      }
      T = g;
    }
  }
  int knn[KK];
#pragma unroll
  for (int k = 0; k < KK; ++k) {
    const u64 g = wave_min_u64(kb[0]);
    if (kb[0] == g) {
#pragma unroll
      for (int i = 0; i < KK - 1; ++i) kb[i] = kb[i + 1];
      kb[KK - 1] = ~0ULL;
    }
    knn[k] = (int)(unsigned)(g & 0xffffffffULL);
  }
  const float* fb = features + (size_t)b * NN * CC;
  float* ob = out + (size_t)center * KK * CC;
#pragma unroll
  for (int k = 0; k < KK; ++k) ob[k * CC + lane] = fb[(size_t)knn[k] * CC + lane];
}

// ======================= launch =======================
extern "C" void kernel_launch(void* const* d_in, const int* in_sizes, int n_in,
                              void* d_out, int out_size, void* d_ws, size_t ws_size,
                              hipStream_t stream) {
  const float* points   = (const float*)d_in[0];
  const float* features = (const float*)d_in[1];
  const int*   cidx     = (const int*)d_in[2];
  float* out = (float*)d_out;

  char* w = (char*)d_ws;
  const size_t off_counts  = 256;   // ints 0..63 reserved: [0]=maxcnt
  const size_t off_cstart  = off_counts + (size_t)BB * MM * 4;
  const size_t off_sorted  = (off_cstart + (size_t)BB * (NC + 1) * 4 + 15) & ~(size_t)15;
  const size_t need        = off_sorted + (size_t)BB * NN * 16;

  int* maxcnt = (int*)w;            // zeroed by build4 each call
  dim3 block(256);

  if (ws_size >= need) {
    int* counts     = (int*)(w + off_counts);
    int* cell_start = (int*)(w + off_cstart);
    float4* sorted  = (float4*)(w + off_sorted);

    build4_kernel<<<dim3(BB), dim3(1024), 0, stream>>>(points, cell_start, sorted, maxcnt);
    grid_count_kernel<<<dim3(BB * MM / 16), block, 0, stream>>>(
        points, cidx, cell_start, sorted, counts, maxcnt);
    grid_topk_kernel<<<dim3(BB * MM / WAVES), block, 0, stream>>>(
        points, features, cidx, counts, maxcnt, cell_start, sorted, out);
  } else {
    int* counts = (int*)w + 64;
    hipMemsetAsync(maxcnt, 0, sizeof(int), stream);
    fb_count_kernel<<<dim3(BB * MM / WAVES), block, 0, stream>>>(points, cidx, counts, maxcnt);
    fb_topk_kernel<<<dim3(BB * MM / WAVES), block, 0, stream>>>(points, features, cidx, counts, maxcnt, out);
  }
}

// Round 15
// 61.778 us; speedup vs baseline: 1.5246x; 1.5246x over previous
//
#include <hip/hip_runtime.h>
#include <stdint.h>

#define BB 4
#define NN 16384
#define MM 2048
#define CC 64
#define KK 16
#define WAVES 4
#define G 16
#define NC (G * G * G)
#define SCAP 128
#define CAP 512

typedef unsigned long long u64;
typedef unsigned int u32;
typedef unsigned short u16;
typedef unsigned char u8;

// distance from scalar c to cell interval [cell/G, (cell+1)/G]
__device__ __forceinline__ float axdist(float c, int cell) {
  const float lo = (float)cell * (1.0f / (float)G);
  const float hi = (float)(cell + 1) * (1.0f / (float)G);
  float d = 0.0f;
  if (c < lo) d = lo - c;
  else if (c > hi) d = c - hi;
  return d;
}

#define LGKM_WAIT() __asm__ volatile("s_waitcnt lgkmcnt(0)" ::: "memory")

__device__ __forceinline__ u64 wave_min_u64(u64 v) {
#pragma unroll
  for (int off = 32; off > 0; off >>= 1) {
    u64 o = __shfl_xor(v, off, 64);
    v = (o < v) ? o : v;
  }
  return v;
}

// ======================= batch-local grid build: 1 block = 1 batch =======================
__global__ __launch_bounds__(1024) void build4_kernel(
    const float* __restrict__ pts, int* __restrict__ cell_start,
    float4* __restrict__ sorted, int* __restrict__ maxcnt) {
  __shared__ int hist[NC];          // counts, then exclusive starts (cursors)
  __shared__ int wsum[16];
  const int b = blockIdx.x;
  const int t = threadIdx.x;        // 0..1023
  const int lane = t & 63;
  const int wave = t >> 6;

  if (b == 0 && t == 0) *maxcnt = 0;   // kernel boundary orders this vs grid_count

  for (int i = t; i < NC; i += 1024) hist[i] = 0;
  __syncthreads();

  // ---- count: 16 points per thread ----
  const float* pb = pts + (size_t)b * NN * 3;
  int mycell[16];
#pragma unroll
  for (int j = 0; j < 16; ++j) {
    const int i = t + j * 1024;
    const float x = pb[i * 3 + 0], y = pb[i * 3 + 1], z = pb[i * 3 + 2];
    int ix = (int)(x * (float)G); ix = ix < 0 ? 0 : (ix > G - 1 ? G - 1 : ix);
    int iy = (int)(y * (float)G); iy = iy < 0 ? 0 : (iy > G - 1 ? G - 1 : iy);
    int iz = (int)(z * (float)G); iz = iz < 0 ? 0 : (iz > G - 1 ? G - 1 : iz);
    const int cell = (iz * G + iy) * G + ix;
    mycell[j] = cell;
    atomicAdd(&hist[cell], 1);
  }
  __syncthreads();

  // ---- scan: thread t owns cells [4t, 4t+4) ----
  const int base = t * 4;
  const int l0 = hist[base], l1 = hist[base + 1], l2 = hist[base + 2], l3 = hist[base + 3];
  const int s4 = l0 + l1 + l2 + l3;
  u32 inc = (u32)s4;
#pragma unroll
  for (int off = 1; off < 64; off <<= 1) {
    u32 tt = __shfl_up(inc, off, 64);
    if (lane >= off) inc += tt;
  }
  if (lane == 63) wsum[wave] = (int)inc;
  __syncthreads();
  u32 woff = 0;
  for (int w2 = 0; w2 < wave; ++w2) woff += (u32)wsum[w2];
  const int ex = (int)(woff + inc - (u32)s4);
  hist[base] = ex;
  hist[base + 1] = ex + l0;
  hist[base + 2] = ex + l0 + l1;
  hist[base + 3] = ex + l0 + l1 + l2;
  int* st = cell_start + b * (NC + 1);
  st[base] = ex;
  st[base + 1] = ex + l0;
  st[base + 2] = ex + l0 + l1;
  st[base + 3] = ex + l0 + l1 + l2;
  if (t == 0) st[NC] = NN;
  __syncthreads();

  // ---- fill: LDS cursor bump + global scatter ----
  float4* sp = sorted + (size_t)b * NN;
#pragma unroll
  for (int j = 0; j < 16; ++j) {
    const int i = t + j * 1024;
    const float x = pb[i * 3 + 0], y = pb[i * 3 + 1], z = pb[i * 3 + 2];
    const int pos = atomicAdd(&hist[mycell[j]], 1);
    sp[pos] = make_float4(x, y, z, __uint_as_float((u32)i));
  }
}

// ======================= density count: 16 lanes per center =======================
__global__ __launch_bounds__(256) void grid_count_kernel(
    const float* __restrict__ points, const int* __restrict__ cidx,
    const int* __restrict__ cell_start, const float4* __restrict__ sorted,
    int* __restrict__ counts, int* __restrict__ maxcnt) {
#pragma clang fp contract(off)
  __shared__ int bmax;
  const int sub = threadIdx.x & 15;
  const int grp = threadIdx.x >> 4;
  const int center = blockIdx.x * 16 + grp;
  const int b = center >> 11;
  if (threadIdx.x == 0) bmax = 0;
  __syncthreads();
  const float* pb = points + (size_t)b * (NN * 3);
  const int ci = cidx[center];
  const float ccx = pb[ci * 3 + 0], ccy = pb[ci * 3 + 1], ccz = pb[ci * 3 + 2];
  const float R0 = 0.05f;
  const float rc = R0 * 1.0001f + 1e-6f;
  const float rc2 = rc * rc;
  const int lox = max(0, (int)floorf((ccx - rc) * (float)G));
  const int hix = min(G - 1, (int)floorf((ccx + rc) * (float)G));
  const int loy = max(0, (int)floorf((ccy - rc) * (float)G));
  const int hiy = min(G - 1, (int)floorf((ccy + rc) * (float)G));
  const int loz = max(0, (int)floorf((ccz - rc) * (float)G));
  const int hiz = min(G - 1, (int)floorf((ccz + rc) * (float)G));
  const int cs0 = b * (NC + 1);
  const float4* sp = sorted + (size_t)b * NN;
  int cnt = 0;
  for (int zc = loz; zc <= hiz; ++zc) {
    const float dz0 = axdist(ccz, zc);
    for (int yc = loy; yc <= hiy; ++yc) {
      const float dy0 = axdist(ccy, yc);
      const float dd = dy0 * dy0 + dz0 * dz0;
      if (dd >= rc2) continue;
      const float half = sqrtf(rc2 - dd) * 1.0001f + 1e-6f;
      const int xl = max(lox, (int)floorf((ccx - half) * (float)G));
      const int xh = min(hix, (int)floorf((ccx + half) * (float)G));
      if (xl > xh) continue;
      const int row = cs0 + (zc * G + yc) * G;
      const int s0 = cell_start[row + xl];
      const int e0 = cell_start[row + xh + 1];
      for (int p = s0 + sub; p < e0; p += 16) {
        const float4 pt = sp[p];
        const float dx = pt.x - ccx, dy = pt.y - ccy, dz = pt.z - ccz;
        const float d = sqrtf((dx * dx + dy * dy) + dz * dz);
        cnt += (d < R0) ? 1 : 0;
      }
    }
  }
#pragma unroll
  for (int off = 8; off > 0; off >>= 1) cnt += __shfl_xor(cnt, off, 16);
  if (sub == 0) {
    counts[center] = cnt;
    atomicMax(&bmax, cnt);
  }
  __syncthreads();
  if (threadIdx.x == 0) atomicMax(maxcnt, bmax);
}

// ======================= topk: 3-stage (fast tA -> hist tA -> hist r) =======================
#define WALK(BODY)                                                   \
  {                                                                  \
    int ri = 0;                                                      \
    for (u32 w = (u32)lane; w < T; w += 64) {                        \
      while (rowC[ri + 1] <= w) ++ri;                                \
      const int p = (int)rowS[ri] + (int)(w - rowC[ri]);             \
      const float4 pt = sp[p];                                       \
      const float dx = pt.x - ccx, dy = pt.y - ccy, dz = pt.z - ccz; \
      const float d = sqrtf((dx * dx + dy * dy) + dz * dz);          \
      BODY                                                           \
    }                                                                \
  }

__global__ __launch_bounds__(256, 6) void grid_topk_kernel(
    const float* __restrict__ points, const float* __restrict__ features,
    const int* __restrict__ cidx, const int* __restrict__ counts,
    const int* __restrict__ maxcnt, const int* __restrict__ cell_start,
    const float4* __restrict__ sorted, float* __restrict__ out) {
#pragma clang fp contract(off)
  __shared__ u16 cand_s[WAVES][CAP];
  __shared__ u8  candb_s[WAVES][CAP];
  __shared__ u64 surv_s[WAVES][SCAP + 2];
  __shared__ u32 rowS_s[WAVES][128];
  __shared__ u32 rowC_s[WAVES][128];
  __shared__ u32 hist_s[WAVES][128];           // 32 bins x 4 replicas (hist stages)

  const int lane = threadIdx.x & 63;
  const int wave = threadIdx.x >> 6;
  const int center = blockIdx.x * WAVES + wave;
  const int b = center >> 11;
  u16* cand = cand_s[wave];
  u8*  candb = candb_s[wave];
  u64* surv = surv_s[wave];
  u32* rowS = rowS_s[wave];
  u32* rowC = rowC_s[wave];
  u32* hist = hist_s[wave];
  const u64 lanemask = (((u64)1 << lane) - 1);

  const float* pb = points + (size_t)b * (NN * 3);
  const int ci = cidx[center];
  const float ccx = pb[ci * 3 + 0], ccy = pb[ci * 3 + 1], ccz = pb[ci * 3 + 2];

  const int cnt_c = counts[center];
  const float DENOM = (float)(4.0 / 3.0 * 3.141592653589793 * (0.05 * 0.05 * 0.05) + 1e-8);
  const float dens = (float)cnt_c / DENOM;
  const float dmax = (float)(*maxcnt) / DENOM + 1e-8f;
  const float r = 0.05f + 0.25f * (1.0f - dens / dmax);
  const int cs0 = b * (NC + 1);
  const float4* sp = sorted + (size_t)b * NN;

  // stage radius; expected candidates self-normalize to ~39 for typical density
  const float tA = fminf(r, fmaxf(0.055f,
      0.05f * cbrtf(16.0f / fmaxf((float)cnt_c, 0.5f)) * 1.35f));

  u32 scnt = 0;
  bool skip1 = false;   // set when fast stage is SHORT (need bigger radius, not re-scan at tA)

  for (int attempt = 0; attempt < 3; ++attempt) {
    if (attempt == 1 && skip1) continue;
    const bool fast = (attempt == 0);
    const float t_eff = (attempt == 2) ? r : tA;
    const bool finals = (t_eff >= r);   // can stop with <KK only at full radius
    const float rc = t_eff * 1.0001f + 1e-6f;
    const float rc2 = rc * rc;
    const float bs1 = 32.0f / t_eff;
    const float bs2 = 1024.0f / t_eff;

    const int lox = max(0, (int)floorf((ccx - rc) * (float)G));
    const int hix = min(G - 1, (int)floorf((ccx + rc) * (float)G));
    const int loy = max(0, (int)floorf((ccy - rc) * (float)G));
    const int hiy = min(G - 1, (int)floorf((ccy + rc) * (float)G));
    const int loz = max(0, (int)floorf((ccz - rc) * (float)G));
    const int hiz = min(G - 1, (int)floorf((ccz + rc) * (float)G));

    // ---- phase 1: pruned row table ----
    const int ny = hiy - loy + 1;
    const int nrows = ny * (hiz - loz + 1);
    u32 len0 = 0, len1 = 0, st0 = 0, st1 = 0;
#pragma unroll
    for (int half_i = 0; half_i < 2; ++half_i) {
      const int rr = lane + half_i * 64;
      u32 st = 0, len = 0;
      if (rr < nrows) {
        const int zz = rr / ny, yy = rr - zz * ny;
        const int zc = loz + zz, yc = loy + yy;
        const float dz0 = axdist(ccz, zc);
        const float dy0 = axdist(ccy, yc);
        const float dd = dy0 * dy0 + dz0 * dz0;
        if (dd < rc2) {
          const float half = sqrtf(rc2 - dd) * 1.0001f + 1e-6f;
          const int xl = max(lox, (int)floorf((ccx - half) * (float)G));
          const int xh = min(hix, (int)floorf((ccx + half) * (float)G));
          if (xl <= xh) {
            const int row = cs0 + (zc * G + yc) * G;
            const int s0 = cell_start[row + xl];
            const int e0 = cell_start[row + xh + 1];
            st = (u32)s0; len = (u32)(e0 - s0);
          }
        }
      }
      if (half_i == 0) { st0 = st; len0 = len; } else { st1 = st; len1 = len; }
    }
    u32 a = len0;
#pragma unroll
    for (int off = 1; off < 64; off <<= 1) {
      u32 t = __shfl_up(a, off, 64);
      if (lane >= off) a += t;
    }
    const u32 tot0 = __shfl(a, 63, 64);
    u32 bcum = len1;
#pragma unroll
    for (int off = 1; off < 64; off <<= 1) {
      u32 t = __shfl_up(bcum, off, 64);
      if (lane >= off) bcum += t;
    }
    const u32 T = tot0 + __shfl(bcum, 63, 64);
    rowS[lane] = st0;
    rowS[lane + 64] = st1;
    rowC[lane] = a - len0;
    rowC[lane + 64] = tot0 + bcum - len1;
    LGKM_WAIT();

    if (fast) {
      // ---- FAST: collect exact (d,idx) keys straight into surv (<=SCAP) ----
      u32 scn = 0;
      {
        int riA = 0, riB = 0;
        for (u32 w = (u32)lane; w < T; w += 128) {
          while (rowC[riA + 1] <= w) ++riA;
          const int pA = (int)rowS[riA] + (int)(w - rowC[riA]);
          const float4 ptA = sp[pA];
          const u32 w2 = w + 64;
          const bool hasB = (w2 < T);
          float xB = 4e4f, yB = 4e4f, zB = 4e4f, wB = 0.0f;
          if (hasB) {
            if (riB < riA) riB = riA;
            while (rowC[riB + 1] <= w2) ++riB;
            const int pB = (int)rowS[riB] + (int)(w2 - rowC[riB]);
            const float4 ptB = sp[pB];
            xB = ptB.x; yB = ptB.y; zB = ptB.z; wB = ptB.w;
          }
          const float dxA = ptA.x - ccx, dyA = ptA.y - ccy, dzA = ptA.z - ccz;
          const float dA = sqrtf((dxA * dxA + dyA * dyA) + dzA * dzA);
          const float dxB = xB - ccx, dyB = yB - ccy, dzB = zB - ccz;
          const float dB = sqrtf((dxB * dxB + dyB * dyB) + dzB * dzB);
          const bool accA = dA < t_eff;
          const bool accB = hasB && (dB < t_eff);
          const u64 maskA = __ballot(accA);
          const u64 maskB = __ballot(accB);
          if (accA) {
            const u32 pos = scn + (u32)__popcll(maskA & lanemask);
            if (pos < (u32)SCAP)
              surv[pos] = ((u64)__float_as_uint(dA) << 32) | __float_as_uint(ptA.w);
          }
          const u32 cA = (u32)__popcll(maskA);
          if (accB) {
            const u32 pos = scn + cA + (u32)__popcll(maskB & lanemask);
            if (pos < (u32)SCAP)
              surv[pos] = ((u64)__float_as_uint(dB) << 32) | __float_as_uint(wB);
          }
          scn += cA + (u32)__popcll(maskB);
        }
      }
      scn = (u32)__shfl((int)scn, 0, 64);   // lane 0 runs max iterations -> complete
      LGKM_WAIT();
      if (scn > (u32)SCAP) continue;                      // -> hist at tA (attempt 1)
      if (scn < (u32)KK && !finals) { skip1 = true; continue; }  // -> hist at r (attempt 2)
      scnt = scn;
      break;
    }

    // ---- HIST stages (attempt 1: tA, attempt 2: r): proven machinery ----
    hist[lane] = 0;
    hist[lane + 64] = 0;
    LGKM_WAIT();

    u32 scn = 0;
    {
      int riA = 0, riB = 0;
      for (u32 w = (u32)lane; w < T; w += 128) {
        while (rowC[riA + 1] <= w) ++riA;
        const int pA = (int)rowS[riA] + (int)(w - rowC[riA]);
        const float4 ptA = sp[pA];
        const u32 w2 = w + 64;
        const bool hasB = (w2 < T);
        int pB = 0;
        float xB = 4e4f, yB = 4e4f, zB = 4e4f;
        if (hasB) {
          if (riB < riA) riB = riA;
          while (rowC[riB + 1] <= w2) ++riB;
          pB = (int)rowS[riB] + (int)(w2 - rowC[riB]);
          const float4 ptB = sp[pB];
          xB = ptB.x; yB = ptB.y; zB = ptB.z;
        }
        const float dxA = ptA.x - ccx, dyA = ptA.y - ccy, dzA = ptA.z - ccz;
        const float dA = sqrtf((dxA * dxA + dyA * dyA) + dzA * dzA);
        const float dxB = xB - ccx, dyB = yB - ccy, dzB = zB - ccz;
        const float dB = sqrtf((dxB * dxB + dyB * dyB) + dzB * dzB);
        const bool accA = dA < t_eff;
        const bool accB = hasB && (dB < t_eff);
        const u64 maskA = __ballot(accA);
        const u64 maskB = __ballot(accB);
        if (accA) {
          int bin = (int)(dA * bs1); bin = bin > 31 ? 31 : bin;
          atomicAdd(&hist[((lane & 3) << 5) + bin], 1u);
          const u32 pos = scn + (u32)__popcll(maskA & lanemask);
          if (pos < (u32)CAP) { cand[pos] = (u16)pA; candb[pos] = (u8)bin; }
        }
        const u32 cA = (u32)__popcll(maskA);
        if (accB) {
          int bin = (int)(dB * bs1); bin = bin > 31 ? 31 : bin;
          atomicAdd(&hist[((lane & 3) << 5) + bin], 1u);
          const u32 pos = scn + cA + (u32)__popcll(maskB & lanemask);
          if (pos < (u32)CAP) { cand[pos] = (u16)pB; candb[pos] = (u8)bin; }
        }
        scn += cA + (u32)__popcll(maskB);
      }
    }
    LGKM_WAIT();

    u32 incl = 0;
    if (lane < 32) incl = hist[lane] + hist[lane + 32] + hist[lane + 64] + hist[lane + 96];
#pragma unroll
    for (int off = 1; off < 32; off <<= 1) {
      u32 t = __shfl_up(incl, off, 32);
      if ((lane & 31) >= off) incl += t;
    }
    const u32 total = __shfl(incl, 31, 64);
    const bool overflow = total > (u32)CAP;

    if (total < (u32)KK) {
      if (!finals) continue;          // tA short -> full radius
      for (u32 i = lane; i < total; i += 64) {
        const float4 pt = sp[cand[i]];
        const float dx = pt.x - ccx, dy = pt.y - ccy, dz = pt.z - ccz;
        const float d = sqrtf((dx * dx + dy * dy) + dz * dz);
        surv[i] = ((u64)__float_as_uint(d) << 32) | __float_as_uint(pt.w);
      }
      scnt = total;
      LGKM_WAIT();
      break;
    }

    u64 bm = __ballot(lane < 32 && incl >= (u32)KK);
    const int b1 = (__ffsll(bm) - 1);
    const u32 cnt_b1 = __shfl(incl, b1, 64);
    const u32 pre = (b1 > 0) ? __shfl(incl, b1 - 1, 64) : 0u;

    int b2 = 31;
    const bool need2 = (pre + cnt_b1 > (u32)SCAP);
    if (need2) {
      hist[lane] = 0;
      hist[lane + 64] = 0;
      LGKM_WAIT();
      if (!overflow) {
        for (u32 i = lane; i < total; i += 64) {
          if ((int)candb[i] == b1) {
            const float4 pt = sp[cand[i]];
            const float dx = pt.x - ccx, dy = pt.y - ccy, dz = pt.z - ccz;
            const float d = sqrtf((dx * dx + dy * dy) + dz * dz);
            int o = (int)(d * bs2) - (b1 << 5);
            o = o < 0 ? 0 : (o > 31 ? 31 : o);
            atomicAdd(&hist[((lane & 3) << 5) + o], 1u);
          }
        }
      } else {
        WALK({
          if (d < t_eff) {
            int bin = (int)(d * bs1); bin = bin > 31 ? 31 : bin;
            if (bin == b1) {
              int o = (int)(d * bs2) - (b1 << 5);
              o = o < 0 ? 0 : (o > 31 ? 31 : o);
              atomicAdd(&hist[((lane & 3) << 5) + o], 1u);
            }
          }
        })
      }
      LGKM_WAIT();
      u32 incl2 = 0;
      if (lane < 32) incl2 = hist[lane] + hist[lane + 32] + hist[lane + 64] + hist[lane + 96];
#pragma unroll
      for (int off = 1; off < 32; off <<= 1) {
        u32 t = __shfl_up(incl2, off, 32);
        if ((lane & 31) >= off) incl2 += t;
      }
      const u32 target = (u32)KK - pre;
      u64 bm2 = __ballot(lane < 32 && incl2 >= target);
      b2 = bm2 ? (__ffsll(bm2) - 1) : 31;
    }

    u32 sc = 0;
    if (!overflow) {
      for (u32 i = lane; i < total; i += 64) {
        const int bin = (int)candb[i];
        bool acc2;
        float d = 0.0f;
        u32 pw = 0;
        if (!need2) {
          acc2 = (bin <= b1);
          if (acc2) {
            const float4 pt = sp[cand[i]];
            const float dx = pt.x - ccx, dy = pt.y - ccy, dz = pt.z - ccz;
            d = sqrtf((dx * dx + dy * dy) + dz * dz);
            pw = __float_as_uint(pt.w);
          }
        } else {
          acc2 = (bin < b1);
          if (bin == b1) {
            const float4 pt = sp[cand[i]];
            const float dx = pt.x - ccx, dy = pt.y - ccy, dz = pt.z - ccz;
            d = sqrtf((dx * dx + dy * dy) + dz * dz);
            pw = __float_as_uint(pt.w);
            int o = (int)(d * bs2) - (b1 << 5);
            o = o < 0 ? 0 : (o > 31 ? 31 : o);
            acc2 = (o <= b2);
          } else if (acc2) {
            const float4 pt = sp[cand[i]];
            const float dx = pt.x - ccx, dy = pt.y - ccy, dz = pt.z - ccz;
            d = sqrtf((dx * dx + dy * dy) + dz * dz);
            pw = __float_as_uint(pt.w);
          }
        }
        const u64 mask = __ballot(acc2);
        if (acc2) {
          const u32 pos = sc + (u32)__popcll(mask & lanemask);
          if (pos < (u32)SCAP)
            surv[pos] = ((u64)__float_as_uint(d) << 32) | pw;
        }
        sc += (u32)__popcll(mask);
      }
    } else {
      WALK({
        bool acc2 = false;
        if (d < t_eff) {
          int bin = (int)(d * bs1); bin = bin > 31 ? 31 : bin;
          if (!need2) acc2 = (bin <= b1);
          else {
            int o = (int)(d * bs2) - (b1 << 5);
            o = o < 0 ? 0 : (o > 31 ? 31 : o);
            acc2 = (bin < b1) || (bin == b1 && o <= b2);
          }
        }
        const u64 mask = __ballot(acc2);
        if (acc2) {
          const u32 pos = sc + (u32)__popcll(mask & lanemask);
          if (pos < (u32)SCAP)
            surv[pos] = ((u64)__float_as_uint(d) << 32) | __float_as_uint(pt.w);
        }
        sc += (u32)__popcll(mask);
      })
    }
    sc = (u32)__shfl((int)sc, 0, 64);
    scnt = sc > (u32)SCAP ? (u32)SCAP : sc;
    LGKM_WAIT();
    break;
  }

  // ---- phase 5: fill with lowest-index masked points if short ----
  if (scnt < (u32)KK) {
    for (int base = 0; base < NN && scnt < (u32)KK; base += 64) {
      const int i = base + lane;
      const float x = pb[i * 3 + 0], y = pb[i * 3 + 1], z = pb[i * 3 + 2];
      const float dx = x - ccx, dy = y - ccy, dz = z - ccz;
      const float d = sqrtf((dx * dx + dy * dy) + dz * dz);
      u64 m = __ballot(!(d < r));
      while (m && scnt < (u32)KK) {
        const int t = __ffsll(m) - 1;
        m &= m - 1;
        if (lane == 0)
          surv[scnt] = ((u64)__float_as_uint(1e10f) << 32) | (u32)(base + t);
        scnt++;
      }
    }
    LGKM_WAIT();
  }

  // ---- phase 6: rank-based select of the KK smallest (dist, idx) keys ----
  {
    const u64 k0 = (lane < (int)scnt) ? surv[lane] : ~0ULL;
    const u64 k1 = (lane + 64 < (int)scnt) ? surv[lane + 64] : ~0ULL;
    u32 rank0 = 0, rank1 = 0;
    for (u32 j = 0; j < scnt; ++j) {
      const u64 kj = surv[j];        // wave-uniform broadcast read
      rank0 += (kj < k0) ? 1u : 0u;
      rank1 += (kj < k1) ? 1u : 0u;
    }
    if (lane < (int)scnt && rank0 < (u32)KK) rowS[rank0] = (u32)(k0 & 0xffffffffULL);
    if (lane + 64 < (int)scnt && rank1 < (u32)KK) rowS[rank1] = (u32)(k1 & 0xffffffffULL);
    LGKM_WAIT();
  }

  // ---- phase 7: feature gather, float4 vectorized (16 lanes x 4ch per k) ----
  const float* fb = features + (size_t)b * NN * CC;
  float* ob = out + (size_t)center * KK * CC;
  const int ch4 = (lane & 15) * 4;
  const int ksub = lane >> 4;
#pragma unroll
  for (int kq = 0; kq < 4; ++kq) {
    const int k = kq * 4 + ksub;
    const int nk = (int)rowS[k];
    const float4 v = *(const float4*)(fb + (size_t)nk * CC + ch4);
    *(float4*)(ob + (size_t)k * CC + ch4) = v;
  }
}

// ======================= fallback (round-1, proven) =======================
#define CH 4096
#define NCHUNK (NN / CH)

__global__ __launch_bounds__(256) void fb_count_kernel(
    const float* __restrict__ points, const int* __restrict__ cidx,
    int* __restrict__ counts, int* __restrict__ maxcnt) {
#pragma clang fp contract(off)
  __shared__ float s[CH * 3];
  const int lane = threadIdx.x & 63;
  const int wave = threadIdx.x >> 6;
  const int center = blockIdx.x * WAVES + wave;
  const int b = center >> 11;
  const float* pb = points + (size_t)b * (NN * 3);
  const int ci = cidx[center];
  const float cx = pb[ci * 3 + 0], cy = pb[ci * 3 + 1], cz = pb[ci * 3 + 2];
  int cnt = 0;
  for (int c = 0; c < NCHUNK; ++c) {
    __syncthreads();
    const float4* src = (const float4*)(pb + (size_t)c * CH * 3);
    float4* dst = (float4*)s;
    for (int i = threadIdx.x; i < CH * 3 / 4; i += 256) dst[i] = src[i];
    __syncthreads();
    for (int j = 0; j < CH / 64; ++j) {
      const int p = j * 64 + lane;
      const float dx = s[p * 3 + 0] - cx;
      const float dy = s[p * 3 + 1] - cy;
      const float dz = s[p * 3 + 2] - cz;
      const float d = sqrtf((dx * dx + dy * dy) + dz * dz);
      cnt += (d < 0.05f) ? 1 : 0;
    }
  }
#pragma unroll
  for (int off = 32; off > 0; off >>= 1) cnt += __shfl_xor(cnt, off, 64);
  if (lane == 0) { counts[center] = cnt; atomicMax(maxcnt, cnt); }
}

__global__ __launch_bounds__(256) void fb_topk_kernel(
    const float* __restrict__ points, const float* __restrict__ features,
    const int* __restrict__ cidx, const int* __restrict__ counts,
    const int* __restrict__ maxcnt, float* __restrict__ out) {
#pragma clang fp contract(off)
  __shared__ float s[CH * 3];
  const int lane = threadIdx.x & 63;
  const int wave = threadIdx.x >> 6;
  const int center = blockIdx.x * WAVES + wave;
  const int b = center >> 11;
  const float* pb = points + (size_t)b * (NN * 3);
  const int ci = cidx[center];
  const float cx = pb[ci * 3 + 0], cy = pb[ci * 3 + 1], cz = pb[ci * 3 + 2];
  const float DENOM = (float)(4.0 / 3.0 * 3.141592653589793 * (0.05 * 0.05 * 0.05) + 1e-8);
  const float dens = (float)counts[center] / DENOM;
  const float dmax = (float)(*maxcnt) / DENOM + 1e-8f;
  const float r = 0.05f + 0.25f * (1.0f - dens / dmax);
  u64 kb[KK];
#pragma unroll
  for (int i = 0; i < KK; ++i) kb[i] = ~0ULL;
  u64 worst = ~0ULL, T = ~0ULL;
  for (int c = 0; c < NCHUNK; ++c) {
    __syncthreads();
    const float4* src = (const float4*)(pb + (size_t)c * CH * 3);
    float4* dst = (float4*)s;
    for (int i = threadIdx.x; i < CH * 3 / 4; i += 256) dst[i] = src[i];
    __syncthreads();
    const int nbase = c * CH;
    for (int j = 0; j < CH / 64; ++j) {
      const int p = j * 64 + lane;
      const float dx = s[p * 3 + 0] - cx;
      const float dy = s[p * 3 + 1] - cy;
      const float dz = s[p * 3 + 2] - cz;
      const float d = sqrtf((dx * dx + dy * dy) + dz * dz);
      const float dm = (d < r) ? d : 1e10f;
      const u64 key = ((u64)__float_as_uint(dm) << 32) | (unsigned)(nbase + p);
      if (key < T && key < worst) {
        u64 cc = key;
#pragma unroll
        for (int i = 0; i < KK; ++i) {
          const bool lt = kb[i] < cc;
          const u64 lo = lt ? kb[i] : cc;
          const u64 hi = lt ? cc : kb[i];
          kb[i] = lo; cc = hi;
        }
        worst = kb[KK - 1];
      }
    }
    if (c == 0) {
      u64 t[KK];
#pragma unroll
      for (int i = 0; i < KK; ++i) t[i] = kb[i];
      u64 g = 0;
#pragma unroll
      for (int k = 0; k < KK; ++k) {
        g = wave_min_u64(t[0]);
        if (t[0] == g) {
#pragma unroll
          for (int i = 0; i < KK - 1; ++i) t[i] = t[i + 1];
          t[KK - 1] = ~0ULL;
        }
      }
      T = g;
    }
  }
  int knn[KK];
#pragma unroll
  for (int k = 0; k < KK; ++k) {
    const u64 g = wave_min_u64(kb[0]);
    if (kb[0] == g) {
#pragma unroll
      for (int i = 0; i < KK - 1; ++i) kb[i] = kb[i + 1];
      kb[KK - 1] = ~0ULL;
    }
    knn[k] = (int)(unsigned)(g & 0xffffffffULL);
  }
  const float* fb = features + (size_t)b * NN * CC;
  float* ob = out + (size_t)center * KK * CC;
#pragma unroll
  for (int k = 0; k < KK; ++k) ob[k * CC + lane] = fb[(size_t)knn[k] * CC + lane];
}

// ======================= launch =======================
extern "C" void kernel_launch(void* const* d_in, const int* in_sizes, int n_in,
                              void* d_out, int out_size, void* d_ws, size_t ws_size,
                              hipStream_t stream) {
  const float* points   = (const float*)d_in[0];
  const float* features = (const float*)d_in[1];
  const int*   cidx     = (const int*)d_in[2];
  float* out = (float*)d_out;

  char* w = (char*)d_ws;
  const size_t off_counts  = 256;   // ints 0..63 reserved: [0]=maxcnt
  const size_t off_cstart  = off_counts + (size_t)BB * MM * 4;
  const size_t off_sorted  = (off_cstart + (size_t)BB * (NC + 1) * 4 + 15) & ~(size_t)15;
  const size_t need        = off_sorted + (size_t)BB * NN * 16;

  int* maxcnt = (int*)w;            // zeroed by build4 each call
  dim3 block(256);

  if (ws_size >= need) {
    int* counts     = (int*)(w + off_counts);
    int* cell_start = (int*)(w + off_cstart);
    float4* sorted  = (float4*)(w + off_sorted);

    build4_kernel<<<dim3(BB), dim3(1024), 0, stream>>>(points, cell_start, sorted, maxcnt);
    grid_count_kernel<<<dim3(BB * MM / 16), block, 0, stream>>>(
        points, cidx, cell_start, sorted, counts, maxcnt);
    grid_topk_kernel<<<dim3(BB * MM / WAVES), block, 0, stream>>>(
        points, features, cidx, counts, maxcnt, cell_start, sorted, out);
  } else {
    int* counts = (int*)w + 64;
    hipMemsetAsync(maxcnt, 0, sizeof(int), stream);
    fb_count_kernel<<<dim3(BB * MM / WAVES), block, 0, stream>>>(points, cidx, counts, maxcnt);
    fb_topk_kernel<<<dim3(BB * MM / WAVES), block, 0, stream>>>(points, features, cidx, counts, maxcnt, out);
  }
}

// Round 16
// 58.391 us; speedup vs baseline: 1.6130x; 1.0580x over previous
//
#include <hip/hip_runtime.h>
#include <stdint.h>

#define BB 4
#define NN 16384
#define MM 2048
#define CC 64
#define KK 16
#define WAVES 4
#define G 16
#define NC (G * G * G)
#define SCAP 128
#define CAP 512

typedef unsigned long long u64;
typedef unsigned int u32;
typedef unsigned short u16;
typedef unsigned char u8;

// distance from scalar c to cell interval [cell/G, (cell+1)/G]
__device__ __forceinline__ float axdist(float c, int cell) {
  const float lo = (float)cell * (1.0f / (float)G);
  const float hi = (float)(cell + 1) * (1.0f / (float)G);
  float d = 0.0f;
  if (c < lo) d = lo - c;
  else if (c > hi) d = c - hi;
  return d;
}

#define LGKM_WAIT() __asm__ volatile("s_waitcnt lgkmcnt(0)" ::: "memory")

__device__ __forceinline__ u64 wave_min_u64(u64 v) {
#pragma unroll
  for (int off = 32; off > 0; off >>= 1) {
    u64 o = __shfl_xor(v, off, 64);
    v = (o < v) ? o : v;
  }
  return v;
}

// ======================= batch-local grid build: 1 block = 1 batch =======================
__global__ __launch_bounds__(1024) void build4_kernel(
    const float* __restrict__ pts, int* __restrict__ cell_start,
    float4* __restrict__ sorted, int* __restrict__ maxcnt) {
  __shared__ int hist[NC];          // counts, then exclusive starts (cursors)
  __shared__ int wsum[16];
  const int b = blockIdx.x;
  const int t = threadIdx.x;        // 0..1023
  const int lane = t & 63;
  const int wave = t >> 6;

  if (b == 0 && t == 0) *maxcnt = 0;   // kernel boundary orders this vs grid_count

  for (int i = t; i < NC; i += 1024) hist[i] = 0;
  __syncthreads();

  // ---- count: 16 points per thread ----
  const float* pb = pts + (size_t)b * NN * 3;
  int mycell[16];
#pragma unroll
  for (int j = 0; j < 16; ++j) {
    const int i = t + j * 1024;
    const float x = pb[i * 3 + 0], y = pb[i * 3 + 1], z = pb[i * 3 + 2];
    int ix = (int)(x * (float)G); ix = ix < 0 ? 0 : (ix > G - 1 ? G - 1 : ix);
    int iy = (int)(y * (float)G); iy = iy < 0 ? 0 : (iy > G - 1 ? G - 1 : iy);
    int iz = (int)(z * (float)G); iz = iz < 0 ? 0 : (iz > G - 1 ? G - 1 : iz);
    const int cell = (iz * G + iy) * G + ix;
    mycell[j] = cell;
    atomicAdd(&hist[cell], 1);
  }
  __syncthreads();

  // ---- scan: thread t owns cells [4t, 4t+4) ----
  const int base = t * 4;
  const int l0 = hist[base], l1 = hist[base + 1], l2 = hist[base + 2], l3 = hist[base + 3];
  const int s4 = l0 + l1 + l2 + l3;
  u32 inc = (u32)s4;
#pragma unroll
  for (int off = 1; off < 64; off <<= 1) {
    u32 tt = __shfl_up(inc, off, 64);
    if (lane >= off) inc += tt;
  }
  if (lane == 63) wsum[wave] = (int)inc;
  __syncthreads();
  u32 woff = 0;
  for (int w2 = 0; w2 < wave; ++w2) woff += (u32)wsum[w2];
  const int ex = (int)(woff + inc - (u32)s4);
  hist[base] = ex;
  hist[base + 1] = ex + l0;
  hist[base + 2] = ex + l0 + l1;
  hist[base + 3] = ex + l0 + l1 + l2;
  int* st = cell_start + b * (NC + 1);
  st[base] = ex;
  st[base + 1] = ex + l0;
  st[base + 2] = ex + l0 + l1;
  st[base + 3] = ex + l0 + l1 + l2;
  if (t == 0) st[NC] = NN;
  __syncthreads();

  // ---- fill: LDS cursor bump + global scatter ----
  float4* sp = sorted + (size_t)b * NN;
#pragma unroll
  for (int j = 0; j < 16; ++j) {
    const int i = t + j * 1024;
    const float x = pb[i * 3 + 0], y = pb[i * 3 + 1], z = pb[i * 3 + 2];
    const int pos = atomicAdd(&hist[mycell[j]], 1);
    sp[pos] = make_float4(x, y, z, __uint_as_float((u32)i));
  }
}

// ======================= density count: 16 lanes per center =======================
__global__ __launch_bounds__(256) void grid_count_kernel(
    const float* __restrict__ points, const int* __restrict__ cidx,
    const int* __restrict__ cell_start, const float4* __restrict__ sorted,
    int* __restrict__ counts, int* __restrict__ maxcnt) {
#pragma clang fp contract(off)
  __shared__ int bmax;
  const int sub = threadIdx.x & 15;
  const int grp = threadIdx.x >> 4;
  const int center = blockIdx.x * 16 + grp;
  const int b = center >> 11;
  if (threadIdx.x == 0) bmax = 0;
  __syncthreads();
  const float* pb = points + (size_t)b * (NN * 3);
  const int ci = cidx[center];
  const float ccx = pb[ci * 3 + 0], ccy = pb[ci * 3 + 1], ccz = pb[ci * 3 + 2];
  const float R0 = 0.05f;
  const float rc = R0 * 1.0001f + 1e-6f;
  const float rc2 = rc * rc;
  const int lox = max(0, (int)floorf((ccx - rc) * (float)G));
  const int hix = min(G - 1, (int)floorf((ccx + rc) * (float)G));
  const int loy = max(0, (int)floorf((ccy - rc) * (float)G));
  const int hiy = min(G - 1, (int)floorf((ccy + rc) * (float)G));
  const int loz = max(0, (int)floorf((ccz - rc) * (float)G));
  const int hiz = min(G - 1, (int)floorf((ccz + rc) * (float)G));
  const int cs0 = b * (NC + 1);
  const float4* sp = sorted + (size_t)b * NN;
  int cnt = 0;
  for (int zc = loz; zc <= hiz; ++zc) {
    const float dz0 = axdist(ccz, zc);
    for (int yc = loy; yc <= hiy; ++yc) {
      const float dy0 = axdist(ccy, yc);
      const float dd = dy0 * dy0 + dz0 * dz0;
      if (dd >= rc2) continue;
      const float half = sqrtf(rc2 - dd) * 1.0001f + 1e-6f;
      const int xl = max(lox, (int)floorf((ccx - half) * (float)G));
      const int xh = min(hix, (int)floorf((ccx + half) * (float)G));
      if (xl > xh) continue;
      const int row = cs0 + (zc * G + yc) * G;
      const int s0 = cell_start[row + xl];
      const int e0 = cell_start[row + xh + 1];
      for (int p = s0 + sub; p < e0; p += 16) {
        const float4 pt = sp[p];
        const float dx = pt.x - ccx, dy = pt.y - ccy, dz = pt.z - ccz;
        const float d = sqrtf((dx * dx + dy * dy) + dz * dz);
        cnt += (d < R0) ? 1 : 0;
      }
    }
  }
#pragma unroll
  for (int off = 8; off > 0; off >>= 1) cnt += __shfl_xor(cnt, off, 16);
  if (sub == 0) {
    counts[center] = cnt;
    atomicMax(&bmax, cnt);
  }
  __syncthreads();
  if (threadIdx.x == 0) atomicMax(maxcnt, bmax);
}

// ======================= topk: two-stage adaptive radius (round-13 proven) =======================
#define WALK(BODY)                                                   \
  {                                                                  \
    int ri = 0;                                                      \
    for (u32 w = (u32)lane; w < T; w += 64) {                        \
      while (rowC[ri + 1] <= w) ++ri;                                \
      const int p = (int)rowS[ri] + (int)(w - rowC[ri]);             \
      const float4 pt = sp[p];                                       \
      const float dx = pt.x - ccx, dy = pt.y - ccy, dz = pt.z - ccz; \
      const float d = sqrtf((dx * dx + dy * dy) + dz * dz);          \
      BODY                                                           \
    }                                                                \
  }

__global__ __launch_bounds__(256, 6) void grid_topk_kernel(
    const float* __restrict__ points, const float* __restrict__ features,
    const int* __restrict__ cidx, const int* __restrict__ counts,
    const int* __restrict__ maxcnt, const int* __restrict__ cell_start,
    const float4* __restrict__ sorted, float* __restrict__ out) {
#pragma clang fp contract(off)
  __shared__ u16 cand_s[WAVES][CAP];
  __shared__ u8  candb_s[WAVES][CAP];
  __shared__ u64 surv_s[WAVES][SCAP + 2];
  __shared__ u32 rowS_s[WAVES][128];
  __shared__ u32 rowC_s[WAVES][128];
  __shared__ u32 hist_s[WAVES][128];           // 32 bins x 4 replicas

  const int lane = threadIdx.x & 63;
  const int wave = threadIdx.x >> 6;
  const int center = blockIdx.x * WAVES + wave;
  const int b = center >> 11;
  u16* cand = cand_s[wave];
  u8*  candb = candb_s[wave];
  u64* surv = surv_s[wave];
  u32* rowS = rowS_s[wave];
  u32* rowC = rowC_s[wave];
  u32* hist = hist_s[wave];
  const u64 lanemask = (((u64)1 << lane) - 1);

  const float* pb = points + (size_t)b * (NN * 3);
  const int ci = cidx[center];
  const float ccx = pb[ci * 3 + 0], ccy = pb[ci * 3 + 1], ccz = pb[ci * 3 + 2];

  const int cnt_c = counts[center];
  const float DENOM = (float)(4.0 / 3.0 * 3.141592653589793 * (0.05 * 0.05 * 0.05) + 1e-8);
  const float dens = (float)cnt_c / DENOM;
  const float dmax = (float)(*maxcnt) / DENOM + 1e-8f;
  const float r = 0.05f + 0.25f * (1.0f - dens / dmax);
  const int cs0 = b * (NC + 1);
  const float4* sp = sorted + (size_t)b * NN;

  // stage-1 radius: provably contains >=16 candidates when cnt_c >= 16
  const float tA = fminf(r, fmaxf(0.055f,
      0.05f * cbrtf(16.0f / fmaxf((float)cnt_c, 0.5f)) * 1.35f));

  u32 scnt = 0;

  for (int attempt = 0; attempt < 2; ++attempt) {
    const float t_eff = (attempt == 0) ? tA : r;
    const bool finals = (attempt == 1) || (tA >= r);
    const float rc = t_eff * 1.0001f + 1e-6f;
    const float rc2 = rc * rc;
    const float bs1 = 32.0f / t_eff;
    const float bs2 = 1024.0f / t_eff;

    const int lox = max(0, (int)floorf((ccx - rc) * (float)G));
    const int hix = min(G - 1, (int)floorf((ccx + rc) * (float)G));
    const int loy = max(0, (int)floorf((ccy - rc) * (float)G));
    const int hiy = min(G - 1, (int)floorf((ccy + rc) * (float)G));
    const int loz = max(0, (int)floorf((ccz - rc) * (float)G));
    const int hiz = min(G - 1, (int)floorf((ccz + rc) * (float)G));

    // ---- phase 1: pruned row table ----
    const int ny = hiy - loy + 1;
    const int nrows = ny * (hiz - loz + 1);
    u32 len0 = 0, len1 = 0, st0 = 0, st1 = 0;
#pragma unroll
    for (int half_i = 0; half_i < 2; ++half_i) {
      const int rr = lane + half_i * 64;
      u32 st = 0, len = 0;
      if (rr < nrows) {
        const int zz = rr / ny, yy = rr - zz * ny;
        const int zc = loz + zz, yc = loy + yy;
        const float dz0 = axdist(ccz, zc);
        const float dy0 = axdist(ccy, yc);
        const float dd = dy0 * dy0 + dz0 * dz0;
        if (dd < rc2) {
          const float half = sqrtf(rc2 - dd) * 1.0001f + 1e-6f;
          const int xl = max(lox, (int)floorf((ccx - half) * (float)G));
          const int xh = min(hix, (int)floorf((ccx + half) * (float)G));
          if (xl <= xh) {
            const int row = cs0 + (zc * G + yc) * G;
            const int s0 = cell_start[row + xl];
            const int e0 = cell_start[row + xh + 1];
            st = (u32)s0; len = (u32)(e0 - s0);
          }
        }
      }
      if (half_i == 0) { st0 = st; len0 = len; } else { st1 = st; len1 = len; }
    }
    u32 a = len0;
#pragma unroll
    for (int off = 1; off < 64; off <<= 1) {
      u32 t = __shfl_up(a, off, 64);
      if (lane >= off) a += t;
    }
    const u32 tot0 = __shfl(a, 63, 64);
    u32 bcum = len1;
#pragma unroll
    for (int off = 1; off < 64; off <<= 1) {
      u32 t = __shfl_up(bcum, off, 64);
      if (lane >= off) bcum += t;
    }
    const u32 T = tot0 + __shfl(bcum, 63, 64);
    rowS[lane] = st0;
    rowS[lane + 64] = st1;
    rowC[lane] = a - len0;
    rowC[lane + 64] = tot0 + bcum - len1;
    hist[lane] = 0;
    hist[lane + 64] = 0;
    LGKM_WAIT();

    // ---- phase 2: flat scan, 2-way ILP; cache u16 pos + u8 bin + histogram ----
    u32 scn = 0;
    {
      int riA = 0, riB = 0;
      for (u32 w = (u32)lane; w < T; w += 128) {
        while (rowC[riA + 1] <= w) ++riA;
        const int pA = (int)rowS[riA] + (int)(w - rowC[riA]);
        const float4 ptA = sp[pA];
        const u32 w2 = w + 64;
        const bool hasB = (w2 < T);
        int pB = 0;
        float xB = 4e4f, yB = 4e4f, zB = 4e4f;
        if (hasB) {
          if (riB < riA) riB = riA;
          while (rowC[riB + 1] <= w2) ++riB;
          pB = (int)rowS[riB] + (int)(w2 - rowC[riB]);
          const float4 ptB = sp[pB];
          xB = ptB.x; yB = ptB.y; zB = ptB.z;
        }
        const float dxA = ptA.x - ccx, dyA = ptA.y - ccy, dzA = ptA.z - ccz;
        const float dA = sqrtf((dxA * dxA + dyA * dyA) + dzA * dzA);
        const float dxB = xB - ccx, dyB = yB - ccy, dzB = zB - ccz;
        const float dB = sqrtf((dxB * dxB + dyB * dyB) + dzB * dzB);
        const bool accA = dA < t_eff;
        const bool accB = hasB && (dB < t_eff);
        const u64 maskA = __ballot(accA);
        const u64 maskB = __ballot(accB);
        if (accA) {
          int bin = (int)(dA * bs1); bin = bin > 31 ? 31 : bin;
          atomicAdd(&hist[((lane & 3) << 5) + bin], 1u);
          const u32 pos = scn + (u32)__popcll(maskA & lanemask);
          if (pos < (u32)CAP) { cand[pos] = (u16)pA; candb[pos] = (u8)bin; }
        }
        const u32 cA = (u32)__popcll(maskA);
        if (accB) {
          int bin = (int)(dB * bs1); bin = bin > 31 ? 31 : bin;
          atomicAdd(&hist[((lane & 3) << 5) + bin], 1u);
          const u32 pos = scn + cA + (u32)__popcll(maskB & lanemask);
          if (pos < (u32)CAP) { cand[pos] = (u16)pB; candb[pos] = (u8)bin; }
        }
        scn += cA + (u32)__popcll(maskB);
      }
    }
    LGKM_WAIT();

    // ---- phase 3: threshold from histogram ----
    u32 incl = 0;
    if (lane < 32) incl = hist[lane] + hist[lane + 32] + hist[lane + 64] + hist[lane + 96];
#pragma unroll
    for (int off = 1; off < 32; off <<= 1) {
      u32 t = __shfl_up(incl, off, 32);
      if ((lane & 31) >= off) incl += t;
    }
    const u32 total = __shfl(incl, 31, 64);
    const bool overflow = total > (u32)CAP;

    if (total < (u32)KK) {
      if (!finals) continue;        // stage 2 with full radius
      for (u32 i = lane; i < total; i += 64) {
        const float4 pt = sp[cand[i]];
        const float dx = pt.x - ccx, dy = pt.y - ccy, dz = pt.z - ccz;
        const float d = sqrtf((dx * dx + dy * dy) + dz * dz);
        surv[i] = ((u64)__float_as_uint(d) << 32) | __float_as_uint(pt.w);
      }
      scnt = total;
      LGKM_WAIT();
      break;
    }

    u64 bm = __ballot(lane < 32 && incl >= (u32)KK);
    const int b1 = (__ffsll(bm) - 1);
    const u32 cnt_b1 = __shfl(incl, b1, 64);
    const u32 pre = (b1 > 0) ? __shfl(incl, b1 - 1, 64) : 0u;

    // rare refine: survivors would overflow surv[]
    int b2 = 31;
    const bool need2 = (pre + cnt_b1 > (u32)SCAP);
    if (need2) {
      hist[lane] = 0;
      hist[lane + 64] = 0;
      LGKM_WAIT();
      if (!overflow) {
        for (u32 i = lane; i < total; i += 64) {
          if ((int)candb[i] == b1) {
            const float4 pt = sp[cand[i]];
            const float dx = pt.x - ccx, dy = pt.y - ccy, dz = pt.z - ccz;
            const float d = sqrtf((dx * dx + dy * dy) + dz * dz);
            int o = (int)(d * bs2) - (b1 << 5);
            o = o < 0 ? 0 : (o > 31 ? 31 : o);
            atomicAdd(&hist[((lane & 3) << 5) + o], 1u);
          }
        }
      } else {
        WALK({
          if (d < t_eff) {
            int bin = (int)(d * bs1); bin = bin > 31 ? 31 : bin;
            if (bin == b1) {
              int o = (int)(d * bs2) - (b1 << 5);
              o = o < 0 ? 0 : (o > 31 ? 31 : o);
              atomicAdd(&hist[((lane & 3) << 5) + o], 1u);
            }
          }
        })
      }
      LGKM_WAIT();
      u32 incl2 = 0;
      if (lane < 32) incl2 = hist[lane] + hist[lane + 32] + hist[lane + 64] + hist[lane + 96];
#pragma unroll
      for (int off = 1; off < 32; off <<= 1) {
        u32 t = __shfl_up(incl2, off, 32);
        if ((lane & 31) >= off) incl2 += t;
      }
      const u32 target = (u32)KK - pre;
      u64 bm2 = __ballot(lane < 32 && incl2 >= target);
      b2 = bm2 ? (__ffsll(bm2) - 1) : 31;
    }

    // ---- phase 4: survivor compaction ----
    u32 sc = 0;
    if (!overflow) {
      for (u32 i = lane; i < total; i += 64) {
        const int bin = (int)candb[i];
        bool acc2;
        float d = 0.0f;
        u32 pw = 0;
        if (!need2) {
          acc2 = (bin <= b1);
          if (acc2) {
            const float4 pt = sp[cand[i]];
            const float dx = pt.x - ccx, dy = pt.y - ccy, dz = pt.z - ccz;
            d = sqrtf((dx * dx + dy * dy) + dz * dz);
            pw = __float_as_uint(pt.w);
          }
        } else {
          acc2 = (bin < b1);
          if (bin == b1) {
            const float4 pt = sp[cand[i]];
            const float dx = pt.x - ccx, dy = pt.y - ccy, dz = pt.z - ccz;
            d = sqrtf((dx * dx + dy * dy) + dz * dz);
            pw = __float_as_uint(pt.w);
            int o = (int)(d * bs2) - (b1 << 5);
            o = o < 0 ? 0 : (o > 31 ? 31 : o);
            acc2 = (o <= b2);
          } else if (acc2) {
            const float4 pt = sp[cand[i]];
            const float dx = pt.x - ccx, dy = pt.y - ccy, dz = pt.z - ccz;
            d = sqrtf((dx * dx + dy * dy) + dz * dz);
            pw = __float_as_uint(pt.w);
          }
        }
        const u64 mask = __ballot(acc2);
        if (acc2) {
          const u32 pos = sc + (u32)__popcll(mask & lanemask);
          if (pos < (u32)SCAP)
            surv[pos] = ((u64)__float_as_uint(d) << 32) | pw;
        }
        sc += (u32)__popcll(mask);
      }
    } else {
      WALK({
        bool acc2 = false;
        if (d < t_eff) {
          int bin = (int)(d * bs1); bin = bin > 31 ? 31 : bin;
          if (!need2) acc2 = (bin <= b1);
          else {
            int o = (int)(d * bs2) - (b1 << 5);
            o = o < 0 ? 0 : (o > 31 ? 31 : o);
            acc2 = (bin < b1) || (bin == b1 && o <= b2);
          }
        }
        const u64 mask = __ballot(acc2);
        if (acc2) {
          const u32 pos = sc + (u32)__popcll(mask & lanemask);
          if (pos < (u32)SCAP)
            surv[pos] = ((u64)__float_as_uint(d) << 32) | __float_as_uint(pt.w);
        }
        sc += (u32)__popcll(mask);
      })
    }
    // lane 0 participates in every iteration -> its count is complete
    sc = (u32)__shfl((int)sc, 0, 64);
    scnt = sc > (u32)SCAP ? (u32)SCAP : sc;
    LGKM_WAIT();
    break;
  }

  // ---- phase 5: fill with lowest-index masked points if short ----
  if (scnt < (u32)KK) {
    for (int base = 0; base < NN && scnt < (u32)KK; base += 64) {
      const int i = base + lane;
      const float x = pb[i * 3 + 0], y = pb[i * 3 + 1], z = pb[i * 3 + 2];
      const float dx = x - ccx, dy = y - ccy, dz = z - ccz;
      const float d = sqrtf((dx * dx + dy * dy) + dz * dz);
      u64 m = __ballot(!(d < r));
      while (m && scnt < (u32)KK) {
        const int t = __ffsll(m) - 1;
        m &= m - 1;
        if (lane == 0)
          surv[scnt] = ((u64)__float_as_uint(1e10f) << 32) | (u32)(base + t);
        scnt++;
      }
    }
    LGKM_WAIT();
  }

  // ---- phase 6: rank-based select of the KK smallest (dist, idx) keys ----
  {
    const u64 k0 = (lane < (int)scnt) ? surv[lane] : ~0ULL;
    const u64 k1 = (lane + 64 < (int)scnt) ? surv[lane + 64] : ~0ULL;
    u32 rank0 = 0, rank1 = 0;
    for (u32 j = 0; j < scnt; ++j) {
      const u64 kj = surv[j];        // wave-uniform broadcast read
      rank0 += (kj < k0) ? 1u : 0u;
      rank1 += (kj < k1) ? 1u : 0u;
    }
    if (lane < (int)scnt && rank0 < (u32)KK) rowS[rank0] = (u32)(k0 & 0xffffffffULL);
    if (lane + 64 < (int)scnt && rank1 < (u32)KK) rowS[rank1] = (u32)(k1 & 0xffffffffULL);
    LGKM_WAIT();
  }

  // ---- phase 7: feature gather, float4 vectorized (16 lanes x 4ch per k) ----
  const float* fb = features + (size_t)b * NN * CC;
  float* ob = out + (size_t)center * KK * CC;
  const int ch4 = (lane & 15) * 4;
  const int ksub = lane >> 4;
#pragma unroll
  for (int kq = 0; kq < 4; ++kq) {
    const int k = kq * 4 + ksub;
    const int nk = (int)rowS[k];
    const float4 v = *(const float4*)(fb + (size_t)nk * CC + ch4);
    *(float4*)(ob + (size_t)k * CC + ch4) = v;
  }
}

// ======================= fallback (round-1, proven) =======================
#define CH 4096
#define NCHUNK (NN / CH)

__global__ __launch_bounds__(256) void fb_count_kernel(
    const float* __restrict__ points, const int* __restrict__ cidx,
    int* __restrict__ counts, int* __restrict__ maxcnt) {
#pragma clang fp contract(off)
  __shared__ float s[CH * 3];
  const int lane = threadIdx.x & 63;
  const int wave = threadIdx.x >> 6;
  const int center = blockIdx.x * WAVES + wave;
  const int b = center >> 11;
  const float* pb = points + (size_t)b * (NN * 3);
  const int ci = cidx[center];
  const float cx = pb[ci * 3 + 0], cy = pb[ci * 3 + 1], cz = pb[ci * 3 + 2];
  int cnt = 0;
  for (int c = 0; c < NCHUNK; ++c) {
    __syncthreads();
    const float4* src = (const float4*)(pb + (size_t)c * CH * 3);
    float4* dst = (float4*)s;
    for (int i = threadIdx.x; i < CH * 3 / 4; i += 256) dst[i] = src[i];
    __syncthreads();
    for (int j = 0; j < CH / 64; ++j) {
      const int p = j * 64 + lane;
      const float dx = s[p * 3 + 0] - cx;
      const float dy = s[p * 3 + 1] - cy;
      const float dz = s[p * 3 + 2] - cz;
      const float d = sqrtf((dx * dx + dy * dy) + dz * dz);
      cnt += (d < 0.05f) ? 1 : 0;
    }
  }
#pragma unroll
  for (int off = 32; off > 0; off >>= 1) cnt += __shfl_xor(cnt, off, 64);
  if (lane == 0) { counts[center] = cnt; atomicMax(maxcnt, cnt); }
}

__global__ __launch_bounds__(256) void fb_topk_kernel(
    const float* __restrict__ points, const float* __restrict__ features,
    const int* __restrict__ cidx, const int* __restrict__ counts,
    const int* __restrict__ maxcnt, float* __restrict__ out) {
#pragma clang fp contract(off)
  __shared__ float s[CH * 3];
  const int lane = threadIdx.x & 63;
  const int wave = threadIdx.x >> 6;
  const int center = blockIdx.x * WAVES + wave;
  const int b = center >> 11;
  const float* pb = points + (size_t)b * (NN * 3);
  const int ci = cidx[center];
  const float cx = pb[ci * 3 + 0], cy = pb[ci * 3 + 1], cz = pb[ci * 3 + 2];
  const float DENOM = (float)(4.0 / 3.0 * 3.141592653589793 * (0.05 * 0.05 * 0.05) + 1e-8);
  const float dens = (float)counts[center] / DENOM;
  const float dmax = (float)(*maxcnt) / DENOM + 1e-8f;
  const float r = 0.05f + 0.25f * (1.0f - dens / dmax);
  u64 kb[KK];
#pragma unroll
  for (int i = 0; i < KK; ++i) kb[i] = ~0ULL;
  u64 worst = ~0ULL, T = ~0ULL;
  for (int c = 0; c < NCHUNK; ++c) {
    __syncthreads();
    const float4* src = (const float4*)(pb + (size_t)c * CH * 3);
    float4* dst = (float4*)s;
    for (int i = threadIdx.x; i < CH * 3 / 4; i += 256) dst[i] = src[i];
    __syncthreads();
    const int nbase = c * CH;
    for (int j = 0; j < CH / 64; ++j) {
      const int p = j * 64 + lane;
      const float dx = s[p * 3 + 0] - cx;
      const float dy = s[p * 3 + 1] - cy;
      const float dz = s[p * 3 + 2] - cz;
      const float d = sqrtf((dx * dx + dy * dy) + dz * dz);
      const float dm = (d < r) ? d : 1e10f;
      const u64 key = ((u64)__float_as_uint(dm) << 32) | (unsigned)(nbase + p);
      if (key < T && key < worst) {
        u64 cc = key;
#pragma unroll
        for (int i = 0; i < KK; ++i) {
          const bool lt = kb[i] < cc;
          const u64 lo = lt ? kb[i] : cc;
          const u64 hi = lt ? cc : kb[i];
          kb[i] = lo; cc = hi;
        }
        worst = kb[KK - 1];
      }
    }
    if (c == 0) {
      u64 t[KK];
#pragma unroll
      for (int i = 0; i < KK; ++i) t[i] = kb[i];
      u64 g = 0;
#pragma unroll
      for (int k = 0; k < KK; ++k) {
        g = wave_min_u64(t[0]);
        if (t[0] == g) {
#pragma unroll
          for (int i = 0; i < KK - 1; ++i) t[i] = t[i + 1];
          t[KK - 1] = ~0ULL;
        }
      }
      T = g;
    }
  }
  int knn[KK];
#pragma unroll
  for (int k = 0; k < KK; ++k) {
    const u64 g = wave_min_u64(kb[0]);
    if (kb[0] == g) {
#pragma unroll
      for (int i = 0; i < KK - 1; ++i) kb[i] = kb[i + 1];
      kb[KK - 1] = ~0ULL;
    }
    knn[k] = (int)(unsigned)(g & 0xffffffffULL);
  }
  const float* fb = features + (size_t)b * NN * CC;
  float* ob = out + (size_t)center * KK * CC;
#pragma unroll
  for (int k = 0; k < KK; ++k) ob[k * CC + lane] = fb[(size_t)knn[k] * CC + lane];
}

// ======================= launch =======================
extern "C" void kernel_launch(void* const* d_in, const int* in_sizes, int n_in,
                              void* d_out, int out_size, void* d_ws, size_t ws_size,
                              hipStream_t stream) {
  const float* points   = (const float*)d_in[0];
  const float* features = (const float*)d_in[1];
  const int*   cidx     = (const int*)d_in[2];
  float* out = (float*)d_out;

  char* w = (char*)d_ws;
  const size_t off_counts  = 256;   // ints 0..63 reserved: [0]=maxcnt
  const size_t off_cstart  = off_counts + (size_t)BB * MM * 4;
  const size_t off_sorted  = (off_cstart + (size_t)BB * (NC + 1) * 4 + 15) & ~(size_t)15;
  const size_t need        = off_sorted + (size_t)BB * NN * 16;

  int* maxcnt = (int*)w;            // zeroed by build4 each call
  dim3 block(256);

  if (ws_size >= need) {
    int* counts     = (int*)(w + off_counts);
    int* cell_start = (int*)(w + off_cstart);
    float4* sorted  = (float4*)(w + off_sorted);

    build4_kernel<<<dim3(BB), dim3(1024), 0, stream>>>(points, cell_start, sorted, maxcnt);
    grid_count_kernel<<<dim3(BB * MM / 16), block, 0, stream>>>(
        points, cidx, cell_start, sorted, counts, maxcnt);
    grid_topk_kernel<<<dim3(BB * MM / WAVES), block, 0, stream>>>(
        points, features, cidx, counts, maxcnt, cell_start, sorted, out);
  } else {
    int* counts = (int*)w + 64;
    hipMemsetAsync(maxcnt, 0, sizeof(int), stream);
    fb_count_kernel<<<dim3(BB * MM / WAVES), block, 0, stream>>>(points, cidx, counts, maxcnt);
    fb_topk_kernel<<<dim3(BB * MM / WAVES), block, 0, stream>>>(points, features, cidx, counts, maxcnt, out);
  }
}

// Round 17
// 58.083 us; speedup vs baseline: 1.6216x; 1.0053x over previous
//
#include <hip/hip_runtime.h>
#include <stdint.h>

#define BB 4
#define NN 16384
#define MM 2048
#define CC 64
#define KK 16
#define WAVES 4
#define G 16
#define NC (G * G * G)
#define SCAP 128
#define CAP 512

typedef unsigned long long u64;
typedef unsigned int u32;
typedef unsigned short u16;
typedef unsigned char u8;

// distance from scalar c to cell interval [cell/G, (cell+1)/G]
__device__ __forceinline__ float axdist(float c, int cell) {
  const float lo = (float)cell * (1.0f / (float)G);
  const float hi = (float)(cell + 1) * (1.0f / (float)G);
  float d = 0.0f;
  if (c < lo) d = lo - c;
  else if (c > hi) d = c - hi;
  return d;
}

#define LGKM_WAIT() __asm__ volatile("s_waitcnt lgkmcnt(0)" ::: "memory")

__device__ __forceinline__ u64 wave_min_u64(u64 v) {
#pragma unroll
  for (int off = 32; off > 0; off >>= 1) {
    u64 o = __shfl_xor(v, off, 64);
    v = (o < v) ? o : v;
  }
  return v;
}

// ======================= batch-local grid build: 1 block = 1 batch =======================
__global__ __launch_bounds__(1024) void build4_kernel(
    const float* __restrict__ pts, int* __restrict__ cell_start,
    float4* __restrict__ sorted, int* __restrict__ maxcnt) {
  __shared__ int hist[NC];          // counts, then exclusive starts (cursors)
  __shared__ int wsum[16];
  const int b = blockIdx.x;
  const int t = threadIdx.x;        // 0..1023
  const int lane = t & 63;
  const int wave = t >> 6;

  if (b == 0 && t == 0) *maxcnt = 0;   // kernel boundary orders this vs grid_count

  for (int i = t; i < NC; i += 1024) hist[i] = 0;
  __syncthreads();

  // ---- count: 16 points per thread ----
  const float* pb = pts + (size_t)b * NN * 3;
  int mycell[16];
#pragma unroll
  for (int j = 0; j < 16; ++j) {
    const int i = t + j * 1024;
    const float x = pb[i * 3 + 0], y = pb[i * 3 + 1], z = pb[i * 3 + 2];
    int ix = (int)(x * (float)G); ix = ix < 0 ? 0 : (ix > G - 1 ? G - 1 : ix);
    int iy = (int)(y * (float)G); iy = iy < 0 ? 0 : (iy > G - 1 ? G - 1 : iy);
    int iz = (int)(z * (float)G); iz = iz < 0 ? 0 : (iz > G - 1 ? G - 1 : iz);
    const int cell = (iz * G + iy) * G + ix;
    mycell[j] = cell;
    atomicAdd(&hist[cell], 1);
  }
  __syncthreads();

  // ---- scan: thread t owns cells [4t, 4t+4) ----
  const int base = t * 4;
  const int l0 = hist[base], l1 = hist[base + 1], l2 = hist[base + 2], l3 = hist[base + 3];
  const int s4 = l0 + l1 + l2 + l3;
  u32 inc = (u32)s4;
#pragma unroll
  for (int off = 1; off < 64; off <<= 1) {
    u32 tt = __shfl_up(inc, off, 64);
    if (lane >= off) inc += tt;
  }
  if (lane == 63) wsum[wave] = (int)inc;
  __syncthreads();
  u32 woff = 0;
  for (int w2 = 0; w2 < wave; ++w2) woff += (u32)wsum[w2];
  const int ex = (int)(woff + inc - (u32)s4);
  hist[base] = ex;
  hist[base + 1] = ex + l0;
  hist[base + 2] = ex + l0 + l1;
  hist[base + 3] = ex + l0 + l1 + l2;
  int* st = cell_start + b * (NC + 1);
  st[base] = ex;
  st[base + 1] = ex + l0;
  st[base + 2] = ex + l0 + l1;
  st[base + 3] = ex + l0 + l1 + l2;
  if (t == 0) st[NC] = NN;
  __syncthreads();

  // ---- fill: LDS cursor bump + global scatter ----
  float4* sp = sorted + (size_t)b * NN;
#pragma unroll
  for (int j = 0; j < 16; ++j) {
    const int i = t + j * 1024;
    const float x = pb[i * 3 + 0], y = pb[i * 3 + 1], z = pb[i * 3 + 2];
    const int pos = atomicAdd(&hist[mycell[j]], 1);
    sp[pos] = make_float4(x, y, z, __uint_as_float((u32)i));
  }
}

// ======================= density count: 16 lanes per center =======================
__global__ __launch_bounds__(256) void grid_count_kernel(
    const float* __restrict__ points, const int* __restrict__ cidx,
    const int* __restrict__ cell_start, const float4* __restrict__ sorted,
    int* __restrict__ counts, int* __restrict__ maxcnt) {
#pragma clang fp contract(off)
  __shared__ int bmax;
  const int sub = threadIdx.x & 15;
  const int grp = threadIdx.x >> 4;
  const int center = blockIdx.x * 16 + grp;
  const int b = center >> 11;
  if (threadIdx.x == 0) bmax = 0;
  __syncthreads();
  const float* pb = points + (size_t)b * (NN * 3);
  const int ci = cidx[center];
  const float ccx = pb[ci * 3 + 0], ccy = pb[ci * 3 + 1], ccz = pb[ci * 3 + 2];
  const float R0 = 0.05f;
  const float rc = R0 * 1.0001f + 1e-6f;
  const float rc2 = rc * rc;
  const int lox = max(0, (int)floorf((ccx - rc) * (float)G));
  const int hix = min(G - 1, (int)floorf((ccx + rc) * (float)G));
  const int loy = max(0, (int)floorf((ccy - rc) * (float)G));
  const int hiy = min(G - 1, (int)floorf((ccy + rc) * (float)G));
  const int loz = max(0, (int)floorf((ccz - rc) * (float)G));
  const int hiz = min(G - 1, (int)floorf((ccz + rc) * (float)G));
  const int cs0 = b * (NC + 1);
  const float4* sp = sorted + (size_t)b * NN;
  int cnt = 0;
  for (int zc = loz; zc <= hiz; ++zc) {
    const float dz0 = axdist(ccz, zc);
    for (int yc = loy; yc <= hiy; ++yc) {
      const float dy0 = axdist(ccy, yc);
      const float dd = dy0 * dy0 + dz0 * dz0;
      if (dd >= rc2) continue;
      const float half = sqrtf(rc2 - dd) * 1.0001f + 1e-6f;
      const int xl = max(lox, (int)floorf((ccx - half) * (float)G));
      const int xh = min(hix, (int)floorf((ccx + half) * (float)G));
      if (xl > xh) continue;
      const int row = cs0 + (zc * G + yc) * G;
      const int s0 = cell_start[row + xl];
      const int e0 = cell_start[row + xh + 1];
      for (int p = s0 + sub; p < e0; p += 16) {
        const float4 pt = sp[p];
        const float dx = pt.x - ccx, dy = pt.y - ccy, dz = pt.z - ccz;
        const float d = sqrtf((dx * dx + dy * dy) + dz * dz);
        cnt += (d < R0) ? 1 : 0;
      }
    }
  }
#pragma unroll
  for (int off = 8; off > 0; off >>= 1) cnt += __shfl_xor(cnt, off, 16);
  if (sub == 0) {
    counts[center] = cnt;
    atomicMax(&bmax, cnt);
  }
  __syncthreads();
  if (threadIdx.x == 0) atomicMax(maxcnt, bmax);
}

// ======================= topk: two-stage adaptive radius (round-13 proven) =======================
#define WALK(BODY)                                                   \
  {                                                                  \
    int ri = 0;                                                      \
    for (u32 w = (u32)lane; w < T; w += 64) {                        \
      while (rowC[ri + 1] <= w) ++ri;                                \
      const int p = (int)rowS[ri] + (int)(w - rowC[ri]);             \
      const float4 pt = sp[p];                                       \
      const float dx = pt.x - ccx, dy = pt.y - ccy, dz = pt.z - ccz; \
      const float d = sqrtf((dx * dx + dy * dy) + dz * dz);          \
      BODY                                                           \
    }                                                                \
  }

// NOTE round-17 single change: no min-waves arg. (256,6) capped residency at
// 6 blocks/CU although LDS (16.9KB) allows 8-9; bare bound lets the scheduler
// fill to the LDS/wave-slot limit (expect ~8 blocks/CU, 32 waves) without
// forcing the allocator below its natural ~52 VGPR (round-14 lesson).
__global__ __launch_bounds__(256) void grid_topk_kernel(
    const float* __restrict__ points, const float* __restrict__ features,
    const int* __restrict__ cidx, const int* __restrict__ counts,
    const int* __restrict__ maxcnt, const int* __restrict__ cell_start,
    const float4* __restrict__ sorted, float* __restrict__ out) {
#pragma clang fp contract(off)
  __shared__ u16 cand_s[WAVES][CAP];
  __shared__ u8  candb_s[WAVES][CAP];
  __shared__ u64 surv_s[WAVES][SCAP + 2];
  __shared__ u32 rowS_s[WAVES][128];
  __shared__ u32 rowC_s[WAVES][128];
  __shared__ u32 hist_s[WAVES][128];           // 32 bins x 4 replicas

  const int lane = threadIdx.x & 63;
  const int wave = threadIdx.x >> 6;
  const int center = blockIdx.x * WAVES + wave;
  const int b = center >> 11;
  u16* cand = cand_s[wave];
  u8*  candb = candb_s[wave];
  u64* surv = surv_s[wave];
  u32* rowS = rowS_s[wave];
  u32* rowC = rowC_s[wave];
  u32* hist = hist_s[wave];
  const u64 lanemask = (((u64)1 << lane) - 1);

  const float* pb = points + (size_t)b * (NN * 3);
  const int ci = cidx[center];
  const float ccx = pb[ci * 3 + 0], ccy = pb[ci * 3 + 1], ccz = pb[ci * 3 + 2];

  const int cnt_c = counts[center];
  const float DENOM = (float)(4.0 / 3.0 * 3.141592653589793 * (0.05 * 0.05 * 0.05) + 1e-8);
  const float dens = (float)cnt_c / DENOM;
  const float dmax = (float)(*maxcnt) / DENOM + 1e-8f;
  const float r = 0.05f + 0.25f * (1.0f - dens / dmax);
  const int cs0 = b * (NC + 1);
  const float4* sp = sorted + (size_t)b * NN;

  // stage-1 radius: provably contains >=16 candidates when cnt_c >= 16
  const float tA = fminf(r, fmaxf(0.055f,
      0.05f * cbrtf(16.0f / fmaxf((float)cnt_c, 0.5f)) * 1.35f));

  u32 scnt = 0;

  for (int attempt = 0; attempt < 2; ++attempt) {
    const float t_eff = (attempt == 0) ? tA : r;
    const bool finals = (attempt == 1) || (tA >= r);
    const float rc = t_eff * 1.0001f + 1e-6f;
    const float rc2 = rc * rc;
    const float bs1 = 32.0f / t_eff;
    const float bs2 = 1024.0f / t_eff;

    const int lox = max(0, (int)floorf((ccx - rc) * (float)G));
    const int hix = min(G - 1, (int)floorf((ccx + rc) * (float)G));
    const int loy = max(0, (int)floorf((ccy - rc) * (float)G));
    const int hiy = min(G - 1, (int)floorf((ccy + rc) * (float)G));
    const int loz = max(0, (int)floorf((ccz - rc) * (float)G));
    const int hiz = min(G - 1, (int)floorf((ccz + rc) * (float)G));

    // ---- phase 1: pruned row table ----
    const int ny = hiy - loy + 1;
    const int nrows = ny * (hiz - loz + 1);
    u32 len0 = 0, len1 = 0, st0 = 0, st1 = 0;
#pragma unroll
    for (int half_i = 0; half_i < 2; ++half_i) {
      const int rr = lane + half_i * 64;
      u32 st = 0, len = 0;
      if (rr < nrows) {
        const int zz = rr / ny, yy = rr - zz * ny;
        const int zc = loz + zz, yc = loy + yy;
        const float dz0 = axdist(ccz, zc);
        const float dy0 = axdist(ccy, yc);
        const float dd = dy0 * dy0 + dz0 * dz0;
        if (dd < rc2) {
          const float half = sqrtf(rc2 - dd) * 1.0001f + 1e-6f;
          const int xl = max(lox, (int)floorf((ccx - half) * (float)G));
          const int xh = min(hix, (int)floorf((ccx + half) * (float)G));
          if (xl <= xh) {
            const int row = cs0 + (zc * G + yc) * G;
            const int s0 = cell_start[row + xl];
            const int e0 = cell_start[row + xh + 1];
            st = (u32)s0; len = (u32)(e0 - s0);
          }
        }
      }
      if (half_i == 0) { st0 = st; len0 = len; } else { st1 = st; len1 = len; }
    }
    u32 a = len0;
#pragma unroll
    for (int off = 1; off < 64; off <<= 1) {
      u32 t = __shfl_up(a, off, 64);
      if (lane >= off) a += t;
    }
    const u32 tot0 = __shfl(a, 63, 64);
    u32 bcum = len1;
#pragma unroll
    for (int off = 1; off < 64; off <<= 1) {
      u32 t = __shfl_up(bcum, off, 64);
      if (lane >= off) bcum += t;
    }
    const u32 T = tot0 + __shfl(bcum, 63, 64);
    rowS[lane] = st0;
    rowS[lane + 64] = st1;
    rowC[lane] = a - len0;
    rowC[lane + 64] = tot0 + bcum - len1;
    hist[lane] = 0;
    hist[lane + 64] = 0;
    LGKM_WAIT();

    // ---- phase 2: flat scan, 2-way ILP; cache u16 pos + u8 bin + histogram ----
    u32 scn = 0;
    {
      int riA = 0, riB = 0;
      for (u32 w = (u32)lane; w < T; w += 128) {
        while (rowC[riA + 1] <= w) ++riA;
        const int pA = (int)rowS[riA] + (int)(w - rowC[riA]);
        const float4 ptA = sp[pA];
        const u32 w2 = w + 64;
        const bool hasB = (w2 < T);
        int pB = 0;
        float xB = 4e4f, yB = 4e4f, zB = 4e4f;
        if (hasB) {
          if (riB < riA) riB = riA;
          while (rowC[riB + 1] <= w2) ++riB;
          pB = (int)rowS[riB] + (int)(w2 - rowC[riB]);
          const float4 ptB = sp[pB];
          xB = ptB.x; yB = ptB.y; zB = ptB.z;
        }
        const float dxA = ptA.x - ccx, dyA = ptA.y - ccy, dzA = ptA.z - ccz;
        const float dA = sqrtf((dxA * dxA + dyA * dyA) + dzA * dzA);
        const float dxB = xB - ccx, dyB = yB - ccy, dzB = zB - ccz;
        const float dB = sqrtf((dxB * dxB + dyB * dyB) + dzB * dzB);
        const bool accA = dA < t_eff;
        const bool accB = hasB && (dB < t_eff);
        const u64 maskA = __ballot(accA);
        const u64 maskB = __ballot(accB);
        if (accA) {
          int bin = (int)(dA * bs1); bin = bin > 31 ? 31 : bin;
          atomicAdd(&hist[((lane & 3) << 5) + bin], 1u);
          const u32 pos = scn + (u32)__popcll(maskA & lanemask);
          if (pos < (u32)CAP) { cand[pos] = (u16)pA; candb[pos] = (u8)bin; }
        }
        const u32 cA = (u32)__popcll(maskA);
        if (accB) {
          int bin = (int)(dB * bs1); bin = bin > 31 ? 31 : bin;
          atomicAdd(&hist[((lane & 3) << 5) + bin], 1u);
          const u32 pos = scn + cA + (u32)__popcll(maskB & lanemask);
          if (pos < (u32)CAP) { cand[pos] = (u16)pB; candb[pos] = (u8)bin; }
        }
        scn += cA + (u32)__popcll(maskB);
      }
    }
    LGKM_WAIT();

    // ---- phase 3: threshold from histogram ----
    u32 incl = 0;
    if (lane < 32) incl = hist[lane] + hist[lane + 32] + hist[lane + 64] + hist[lane + 96];
#pragma unroll
    for (int off = 1; off < 32; off <<= 1) {
      u32 t = __shfl_up(incl, off, 32);
      if ((lane & 31) >= off) incl += t;
    }
    const u32 total = __shfl(incl, 31, 64);
    const bool overflow = total > (u32)CAP;

    if (total < (u32)KK) {
      if (!finals) continue;        // stage 2 with full radius
      for (u32 i = lane; i < total; i += 64) {
        const float4 pt = sp[cand[i]];
        const float dx = pt.x - ccx, dy = pt.y - ccy, dz = pt.z - ccz;
        const float d = sqrtf((dx * dx + dy * dy) + dz * dz);
        surv[i] = ((u64)__float_as_uint(d) << 32) | __float_as_uint(pt.w);
      }
      scnt = total;
      LGKM_WAIT();
      break;
    }

    u64 bm = __ballot(lane < 32 && incl >= (u32)KK);
    const int b1 = (__ffsll(bm) - 1);
    const u32 cnt_b1 = __shfl(incl, b1, 64);
    const u32 pre = (b1 > 0) ? __shfl(incl, b1 - 1, 64) : 0u;

    // rare refine: survivors would overflow surv[]
    int b2 = 31;
    const bool need2 = (pre + cnt_b1 > (u32)SCAP);
    if (need2) {
      hist[lane] = 0;
      hist[lane + 64] = 0;
      LGKM_WAIT();
      if (!overflow) {
        for (u32 i = lane; i < total; i += 64) {
          if ((int)candb[i] == b1) {
            const float4 pt = sp[cand[i]];
            const float dx = pt.x - ccx, dy = pt.y - ccy, dz = pt.z - ccz;
            const float d = sqrtf((dx * dx + dy * dy) + dz * dz);
            int o = (int)(d * bs2) - (b1 << 5);
            o = o < 0 ? 0 : (o > 31 ? 31 : o);
            atomicAdd(&hist[((lane & 3) << 5) + o], 1u);
          }
        }
      } else {
        WALK({
          if (d < t_eff) {
            int bin = (int)(d * bs1); bin = bin > 31 ? 31 : bin;
            if (bin == b1) {
              int o = (int)(d * bs2) - (b1 << 5);
              o = o < 0 ? 0 : (o > 31 ? 31 : o);
              atomicAdd(&hist[((lane & 3) << 5) + o], 1u);
            }
          }
        })
      }
      LGKM_WAIT();
      u32 incl2 = 0;
      if (lane < 32) incl2 = hist[lane] + hist[lane + 32] + hist[lane + 64] + hist[lane + 96];
#pragma unroll
      for (int off = 1; off < 32; off <<= 1) {
        u32 t = __shfl_up(incl2, off, 32);
        if ((lane & 31) >= off) incl2 += t;
      }
      const u32 target = (u32)KK - pre;
      u64 bm2 = __ballot(lane < 32 && incl2 >= target);
      b2 = bm2 ? (__ffsll(bm2) - 1) : 31;
    }

    // ---- phase 4: survivor compaction ----
    u32 sc = 0;
    if (!overflow) {
      for (u32 i = lane; i < total; i += 64) {
        const int bin = (int)candb[i];
        bool acc2;
        float d = 0.0f;
        u32 pw = 0;
        if (!need2) {
          acc2 = (bin <= b1);
          if (acc2) {
            const float4 pt = sp[cand[i]];
            const float dx = pt.x - ccx, dy = pt.y - ccy, dz = pt.z - ccz;
            d = sqrtf((dx * dx + dy * dy) + dz * dz);
            pw = __float_as_uint(pt.w);
          }
        } else {
          acc2 = (bin < b1);
          if (bin == b1) {
            const float4 pt = sp[cand[i]];
            const float dx = pt.x - ccx, dy = pt.y - ccy, dz = pt.z - ccz;
            d = sqrtf((dx * dx + dy * dy) + dz * dz);
            pw = __float_as_uint(pt.w);
            int o = (int)(d * bs2) - (b1 << 5);
            o = o < 0 ? 0 : (o > 31 ? 31 : o);
            acc2 = (o <= b2);
          } else if (acc2) {
            const float4 pt = sp[cand[i]];
            const float dx = pt.x - ccx, dy = pt.y - ccy, dz = pt.z - ccz;
            d = sqrtf((dx * dx + dy * dy) + dz * dz);
            pw = __float_as_uint(pt.w);
          }
        }
        const u64 mask = __ballot(acc2);
        if (acc2) {
          const u32 pos = sc + (u32)__popcll(mask & lanemask);
          if (pos < (u32)SCAP)
            surv[pos] = ((u64)__float_as_uint(d) << 32) | pw;
        }
        sc += (u32)__popcll(mask);
      }
    } else {
      WALK({
        bool acc2 = false;
        if (d < t_eff) {
          int bin = (int)(d * bs1); bin = bin > 31 ? 31 : bin;
          if (!need2) acc2 = (bin <= b1);
          else {
            int o = (int)(d * bs2) - (b1 << 5);
            o = o < 0 ? 0 : (o > 31 ? 31 : o);
            acc2 = (bin < b1) || (bin == b1 && o <= b2);
          }
        }
        const u64 mask = __ballot(acc2);
        if (acc2) {
          const u32 pos = sc + (u32)__popcll(mask & lanemask);
          if (pos < (u32)SCAP)
            surv[pos] = ((u64)__float_as_uint(d) << 32) | __float_as_uint(pt.w);
        }
        sc += (u32)__popcll(mask);
      })
    }
    // lane 0 participates in every iteration -> its count is complete
    sc = (u32)__shfl((int)sc, 0, 64);
    scnt = sc > (u32)SCAP ? (u32)SCAP : sc;
    LGKM_WAIT();
    break;
  }

  // ---- phase 5: fill with lowest-index masked points if short ----
  if (scnt < (u32)KK) {
    for (int base = 0; base < NN && scnt < (u32)KK; base += 64) {
      const int i = base + lane;
      const float x = pb[i * 3 + 0], y = pb[i * 3 + 1], z = pb[i * 3 + 2];
      const float dx = x - ccx, dy = y - ccy, dz = z - ccz;
      const float d = sqrtf((dx * dx + dy * dy) + dz * dz);
      u64 m = __ballot(!(d < r));
      while (m && scnt < (u32)KK) {
        const int t = __ffsll(m) - 1;
        m &= m - 1;
        if (lane == 0)
          surv[scnt] = ((u64)__float_as_uint(1e10f) << 32) | (u32)(base + t);
        scnt++;
      }
    }
    LGKM_WAIT();
  }

  // ---- phase 6: rank-based select of the KK smallest (dist, idx) keys ----
  {
    const u64 k0 = (lane < (int)scnt) ? surv[lane] : ~0ULL;
    const u64 k1 = (lane + 64 < (int)scnt) ? surv[lane + 64] : ~0ULL;
    u32 rank0 = 0, rank1 = 0;
    for (u32 j = 0; j < scnt; ++j) {
      const u64 kj = surv[j];        // wave-uniform broadcast read
      rank0 += (kj < k0) ? 1u : 0u;
      rank1 += (kj < k1) ? 1u : 0u;
    }
    if (lane < (int)scnt && rank0 < (u32)KK) rowS[rank0] = (u32)(k0 & 0xffffffffULL);
    if (lane + 64 < (int)scnt && rank1 < (u32)KK) rowS[rank1] = (u32)(k1 & 0xffffffffULL);
    LGKM_WAIT();
  }

  // ---- phase 7: feature gather, float4 vectorized (16 lanes x 4ch per k) ----
  const float* fb = features + (size_t)b * NN * CC;
  float* ob = out + (size_t)center * KK * CC;
  const int ch4 = (lane & 15) * 4;
  const int ksub = lane >> 4;
#pragma unroll
  for (int kq = 0; kq < 4; ++kq) {
    const int k = kq * 4 + ksub;
    const int nk = (int)rowS[k];
    const float4 v = *(const float4*)(fb + (size_t)nk * CC + ch4);
    *(float4*)(ob + (size_t)k * CC + ch4) = v;
  }
}

// ======================= fallback (round-1, proven) =======================
#define CH 4096
#define NCHUNK (NN / CH)

__global__ __launch_bounds__(256) void fb_count_kernel(
    const float* __restrict__ points, const int* __restrict__ cidx,
    int* __restrict__ counts, int* __restrict__ maxcnt) {
#pragma clang fp contract(off)
  __shared__ float s[CH * 3];
  const int lane = threadIdx.x & 63;
  const int wave = threadIdx.x >> 6;
  const int center = blockIdx.x * WAVES + wave;
  const int b = center >> 11;
  const float* pb = points + (size_t)b * (NN * 3);
  const int ci = cidx[center];
  const float cx = pb[ci * 3 + 0], cy = pb[ci * 3 + 1], cz = pb[ci * 3 + 2];
  int cnt = 0;
  for (int c = 0; c < NCHUNK; ++c) {
    __syncthreads();
    const float4* src = (const float4*)(pb + (size_t)c * CH * 3);
    float4* dst = (float4*)s;
    for (int i = threadIdx.x; i < CH * 3 / 4; i += 256) dst[i] = src[i];
    __syncthreads();
    for (int j = 0; j < CH / 64; ++j) {
      const int p = j * 64 + lane;
      const float dx = s[p * 3 + 0] - cx;
      const float dy = s[p * 3 + 1] - cy;
      const float dz = s[p * 3 + 2] - cz;
      const float d = sqrtf((dx * dx + dy * dy) + dz * dz);
      cnt += (d < 0.05f) ? 1 : 0;
    }
  }
#pragma unroll
  for (int off = 32; off > 0; off >>= 1) cnt += __shfl_xor(cnt, off, 64);
  if (lane == 0) { counts[center] = cnt; atomicMax(maxcnt, cnt); }
}

__global__ __launch_bounds__(256) void fb_topk_kernel(
    const float* __restrict__ points, const float* __restrict__ features,
    const int* __restrict__ cidx, const int* __restrict__ counts,
    const int* __restrict__ maxcnt, float* __restrict__ out) {
#pragma clang fp contract(off)
  __shared__ float s[CH * 3];
  const int lane = threadIdx.x & 63;
  const int wave = threadIdx.x >> 6;
  const int center = blockIdx.x * WAVES + wave;
  const int b = center >> 11;
  const float* pb = points + (size_t)b * (NN * 3);
  const int ci = cidx[center];
  const float cx = pb[ci * 3 + 0], cy = pb[ci * 3 + 1], cz = pb[ci * 3 + 2];
  const float DENOM = (float)(4.0 / 3.0 * 3.141592653589793 * (0.05 * 0.05 * 0.05) + 1e-8);
  const float dens = (float)counts[center] / DENOM;
  const float dmax = (float)(*maxcnt) / DENOM + 1e-8f;
  const float r = 0.05f + 0.25f * (1.0f - dens / dmax);
  u64 kb[KK];
#pragma unroll
  for (int i = 0; i < KK; ++i) kb[i] = ~0ULL;
  u64 worst = ~0ULL, T = ~0ULL;
  for (int c = 0; c < NCHUNK; ++c) {
    __syncthreads();
    const float4* src = (const float4*)(pb + (size_t)c * CH * 3);
    float4* dst = (float4*)s;
    for (int i = threadIdx.x; i < CH * 3 / 4; i += 256) dst[i] = src[i];
    __syncthreads();
    const int nbase = c * CH;
    for (int j = 0; j < CH / 64; ++j) {
      const int p = j * 64 + lane;
      const float dx = s[p * 3 + 0] - cx;
      const float dy = s[p * 3 + 1] - cy;
      const float dz = s[p * 3 + 2] - cz;
      const float d = sqrtf((dx * dx + dy * dy) + dz * dz);
      const float dm = (d < r) ? d : 1e10f;
      const u64 key = ((u64)__float_as_uint(dm) << 32) | (unsigned)(nbase + p);
      if (key < T && key < worst) {
        u64 cc = key;
#pragma unroll
        for (int i = 0; i < KK; ++i) {
          const bool lt = kb[i] < cc;
          const u64 lo = lt ? kb[i] : cc;
          const u64 hi = lt ? cc : kb[i];
          kb[i] = lo; cc = hi;
        }
        worst = kb[KK - 1];
      }
    }
    if (c == 0) {
      u64 t[KK];
#pragma unroll
      for (int i = 0; i < KK; ++i) t[i] = kb[i];
      u64 g = 0;
#pragma unroll
      for (int k = 0; k < KK; ++k) {
        g = wave_min_u64(t[0]);
        if (t[0] == g) {
#pragma unroll
          for (int i = 0; i < KK - 1; ++i) t[i] = t[i + 1];
          t[KK - 1] = ~0ULL;
        }
      }
      T = g;
    }
  }
  int knn[KK];
#pragma unroll
  for (int k = 0; k < KK; ++k) {
    const u64 g = wave_min_u64(kb[0]);
    if (kb[0] == g) {
#pragma unroll
      for (int i = 0; i < KK - 1; ++i) kb[i] = kb[i + 1];
      kb[KK - 1] = ~0ULL;
    }
    knn[k] = (int)(unsigned)(g & 0xffffffffULL);
  }
  const float* fb = features + (size_t)b * NN * CC;
  float* ob = out + (size_t)center * KK * CC;
#pragma unroll
  for (int k = 0; k < KK; ++k) ob[k * CC + lane] = fb[(size_t)knn[k] * CC + lane];
}

// ======================= launch =======================
extern "C" void kernel_launch(void* const* d_in, const int* in_sizes, int n_in,
                              void* d_out, int out_size, void* d_ws, size_t ws_size,
                              hipStream_t stream) {
  const float* points   = (const float*)d_in[0];
  const float* features = (const float*)d_in[1];
  const int*   cidx     = (const int*)d_in[2];
  float* out = (float*)d_out;

  char* w = (char*)d_ws;
  const size_t off_counts  = 256;   // ints 0..63 reserved: [0]=maxcnt
  const size_t off_cstart  = off_counts + (size_t)BB * MM * 4;
  const size_t off_sorted  = (off_cstart + (size_t)BB * (NC + 1) * 4 + 15) & ~(size_t)15;
  const size_t need        = off_sorted + (size_t)BB * NN * 16;

  int* maxcnt = (int*)w;            // zeroed by build4 each call
  dim3 block(256);

  if (ws_size >= need) {
    int* counts     = (int*)(w + off_counts);
    int* cell_start = (int*)(w + off_cstart);
    float4* sorted  = (float4*)(w + off_sorted);

    build4_kernel<<<dim3(BB), dim3(1024), 0, stream>>>(points, cell_start, sorted, maxcnt);
    grid_count_kernel<<<dim3(BB * MM / 16), block, 0, stream>>>(
        points, cidx, cell_start, sorted, counts, maxcnt);
    grid_topk_kernel<<<dim3(BB * MM / WAVES), block, 0, stream>>>(
        points, features, cidx, counts, maxcnt, cell_start, sorted, out);
  } else {
    int* counts = (int*)w + 64;
    hipMemsetAsync(maxcnt, 0, sizeof(int), stream);
    fb_count_kernel<<<dim3(BB * MM / WAVES), block, 0, stream>>>(points, cidx, counts, maxcnt);
    fb_topk_kernel<<<dim3(BB * MM / WAVES), block, 0, stream>>>(points, features, cidx, counts, maxcnt, out);
  }
}